// Round 7
// baseline (554.087 us; speedup 1.0000x reference)
//
#include <hip/hip_runtime.h>
#include <cstdint>
#include <cstddef>

#define NN 100000
#define EE 1600000
#define DIM 128
#define CAP 48        // ELL row capacity (mean deg 16; P(deg>48) ~ 5e-11 per node)
#define OVF_CAP 512   // overflow edge capacity (expected 0 used)

#define NB 196        // dst buckets of 512 nodes: ceil(100000/512)
#define BSH 9         // log2(nodes per bucket)
#define BCAP 9472     // per-bucket partition capacity (mean 8163, +14 sigma)
#define SLOTS 32      // LDS staging slots per bucket
#define FLUSH_AT 16   // flush threshold (entries)
#define ACHUNK 4096   // edges per phase-A block
#define ATHREADS 512

typedef __attribute__((ext_vector_type(8))) short bf16x8;
typedef __attribute__((ext_vector_type(4))) float f32x4;

__device__ __forceinline__ unsigned short f2bf(float f) {
  union { float f; uint32_t u; } v; v.f = f;
  uint32_t r = v.u + 0x7FFF + ((v.u >> 16) & 1);  // RNE to bf16
  return (unsigned short)(r >> 16);
}
__device__ __forceinline__ float bf2f(unsigned short s) {
  union { uint32_t u; float f; } v; v.u = (uint32_t)s << 16;
  return v.f;
}

// ---------------------------------------------------------------------------
// Phase A: partition edges into NB dst-buckets with LDS staging.
// pack = s | (dl << 17), dl = d & 511  (s < 2^17)
// 512 threads; wave-cooperative flush (lanes write staged entries in
// parallel -> coalesced runs, no LDS bank conflicts on consecutive reads).
// int64-vs-int32 edge dtype self-detected per block (first-wave ballot).
// ---------------------------------------------------------------------------
__global__ __launch_bounds__(ATHREADS) void partA_kernel(
    const void* __restrict__ edges, int* __restrict__ bcnt,
    unsigned* __restrict__ part, int* __restrict__ novf, int* __restrict__ ovf) {
  __shared__ unsigned stage[NB][SLOTS + 1];  // +1 pad: kill bank aliasing
  __shared__ int scnt[NB];
  __shared__ int sh_i64;
  const int t = threadIdx.x;
  const int wv = t >> 6;
  const int lane = t & 63;
  for (int b = t; b < NB; b += ATHREADS) scnt[b] = 0;
  if (t < 64) {
    // int64 little-endian => odd 32-bit words of first 64 entries all zero;
    // int32 => those words are random src values, all-zero impossible.
    int v = ((const int*)edges)[2 * t + 1];
    unsigned long long m = __ballot(v != 0);
    if (t == 0) sh_i64 = (m == 0ull) ? 1 : 0;
  }
  __syncthreads();
  const int i64 = sh_i64;
  const long long ebase = (long long)blockIdx.x * ACHUNK;
  const int nrounds = ACHUNK / ATHREADS;
  for (int r = 0; r < nrounds; ++r) {
    long long e = ebase + (long long)r * ATHREADS + t;
    if (e < EE) {
      int s, d;
      if (i64) {
        s = (int)((const long long*)edges)[e];
        d = (int)((const long long*)edges)[(long long)EE + e];
      } else {
        s = ((const int*)edges)[e];
        d = ((const int*)edges)[(long long)EE + e];
      }
      if ((unsigned)s < NN && (unsigned)d < NN) {
        int b = d >> BSH;
        unsigned pk = (unsigned)s | ((unsigned)(d & ((1 << BSH) - 1)) << 17);
        int pos = atomicAdd(&scnt[b], 1);
        if (pos < SLOTS) {
          stage[b][pos] = pk;
        } else {  // stage overflow (rare): direct append
          int g = atomicAdd(&bcnt[b], 1);
          if (g < BCAP) part[(size_t)b * BCAP + g] = pk;
          else { int oi = atomicAdd(novf, 1); if (oi < OVF_CAP) { ovf[oi*2] = s; ovf[oi*2+1] = d; } }
        }
      }
    }
    __syncthreads();
    const bool last = (r == nrounds - 1);
    for (int b = wv; b < NB; b += ATHREADS / 64) {  // one wave per bucket
      int c = scnt[b];
      if (c > SLOTS) c = SLOTS;
      if (c > 0 && (last || c >= FLUSH_AT)) {
        int g = 0;
        if (lane == 0) g = atomicAdd(&bcnt[b], c);
        g = __shfl(g, 0, 64);
        if (lane < c) {
          int gp = g + lane;
          unsigned pk = stage[b][lane];
          if (gp < BCAP) {
            part[(size_t)b * BCAP + gp] = pk;
          } else {
            int oi = atomicAdd(novf, 1);
            if (oi < OVF_CAP) { ovf[oi*2] = (int)(pk & 0x1FFFF); ovf[oi*2+1] = (b << BSH) | (int)(pk >> 17); }
          }
        }
        if (lane == 0) scnt[b] = 0;
      }
    }
    __syncthreads();
  }
}

// ---------------------------------------------------------------------------
// Phase B: two blocks per bucket (256 nodes each); build ELL rows in LDS
// (LDS atomics), write densely coalesced. Also emits cnt (degree).
// ---------------------------------------------------------------------------
__global__ __launch_bounds__(256) void partB_kernel(
    const int* __restrict__ bcnt, const unsigned* __restrict__ part,
    int* __restrict__ cnt, int* __restrict__ ell,
    int* __restrict__ novf, int* __restrict__ ovf) {
  __shared__ int lcnt[256];
  __shared__ int lell[256 * CAP];  // 48 KB
  const int t = threadIdx.x;
  const int b = blockIdx.x >> 1;
  const int half = blockIdx.x & 1;
  lcnt[t] = 0;
  __syncthreads();
  int n = bcnt[b];
  if (n > BCAP) n = BCAP;
  for (int i = t; i < n; i += 256) {
    unsigned pk = part[(size_t)b * BCAP + i];
    int dl = (int)(pk >> 17);
    if ((dl >> 8) == half) {
      int s = (int)(pk & 0x1FFFF);
      int local = dl & 255;
      int pos = atomicAdd(&lcnt[local], 1);
      if (pos < CAP) lell[local * CAP + pos] = s;
      else { int oi = atomicAdd(novf, 1); if (oi < OVF_CAP) { ovf[oi*2] = s; ovf[oi*2+1] = (b << BSH) | dl; } }
    }
  }
  __syncthreads();
  const int node0 = (b << BSH) + half * 256;
  int4* dst = (int4*)(ell + (size_t)node0 * CAP);
  const int4* src = (const int4*)lell;
#pragma unroll
  for (int i = 0; i < 256 * CAP / 4 / 256; ++i) dst[t + i * 256] = src[t + i * 256];
  int node = node0 + t;
  if (node < NN) cnt[node] = lcnt[t];
}

// ---------------------------------------------------------------------------
// x (f32) -> bf16 hi/lo planes (exact split)
// ---------------------------------------------------------------------------
__global__ void cast2_kernel(const float* __restrict__ x,
                             unsigned short* __restrict__ xhi,
                             unsigned short* __restrict__ xlo) {
  int i = blockIdx.x * 256 + threadIdx.x;  // one float4 per thread
  if (i >= NN * DIM / 4) return;
  f32x4 v = ((const f32x4*)x)[i];
  ushort4 hi, lo;
  hi.x = f2bf(v[0]); lo.x = f2bf(v[0] - bf2f(hi.x));
  hi.y = f2bf(v[1]); lo.y = f2bf(v[1] - bf2f(hi.y));
  hi.z = f2bf(v[2]); lo.z = f2bf(v[2] - bf2f(hi.z));
  hi.w = f2bf(v[3]); lo.w = f2bf(v[3] - bf2f(hi.w));
  ((ushort4*)xhi)[i] = hi;
  ((ushort4*)xlo)[i] = lo;
}

// ---------------------------------------------------------------------------
// Gather-aggregate from ELL (bf16-hi input plane -> bf16-hi agg plane).
// One wave per node; halves take alternating neighbors; lane owns 4 cols.
// ---------------------------------------------------------------------------
__global__ __launch_bounds__(256) void gather_ell_kernel(
    const int* __restrict__ cnt, const int* __restrict__ ell,
    const unsigned short* __restrict__ h, unsigned short* __restrict__ ahi,
    const int* __restrict__ novf, const int* __restrict__ ovf) {
  const int node = blockIdx.x * 4 + (threadIdx.x >> 6);
  const int lane = threadIdx.x & 63;
  const int half = lane >> 5;
  const int c = lane & 31;
  if (node >= NN) return;
  const int dcnt = cnt[node];
  const int n = dcnt < CAP ? dcnt : CAP;
  const int* row = ell + (size_t)node * CAP;
  f32x4 s = {0.f, 0.f, 0.f, 0.f};
  int p = half;
  for (; p + 2 < n; p += 4) {
    int s0 = row[p];
    int s1 = row[p + 2];
    ushort4 v0 = *(const ushort4*)(h + (size_t)s0 * DIM + c * 4);
    ushort4 v1 = *(const ushort4*)(h + (size_t)s1 * DIM + c * 4);
    s[0] += bf2f(v0.x) + bf2f(v1.x);
    s[1] += bf2f(v0.y) + bf2f(v1.y);
    s[2] += bf2f(v0.z) + bf2f(v1.z);
    s[3] += bf2f(v0.w) + bf2f(v1.w);
  }
  if (p < n) {
    ushort4 v0 = *(const ushort4*)(h + (size_t)row[p] * DIM + c * 4);
    s[0] += bf2f(v0.x);
    s[1] += bf2f(v0.y);
    s[2] += bf2f(v0.z);
    s[3] += bf2f(v0.w);
  }
#pragma unroll
  for (int i = 0; i < 4; ++i) s[i] += __shfl_xor(s[i], 32, 64);
  if (half == 0) {
    if (dcnt > CAP) {  // overflow fixup: scan tiny list (expected empty)
      int no = *novf;
      if (no > OVF_CAP) no = OVF_CAP;
      for (int i = 0; i < no; ++i) {
        if (ovf[i * 2 + 1] == node) {
          ushort4 v0 = *(const ushort4*)(h + (size_t)ovf[i * 2] * DIM + c * 4);
          s[0] += bf2f(v0.x);
          s[1] += bf2f(v0.y);
          s[2] += bf2f(v0.z);
          s[3] += bf2f(v0.w);
        }
      }
    }
    const float rd = 1.0f / fmaxf((float)dcnt, 1.0f);
    ushort4 o;
    o.x = f2bf(s[0] * rd);
    o.y = f2bf(s[1] * rd);
    o.z = f2bf(s[2] * rd);
    o.w = f2bf(s[3] * rd);
    *(ushort4*)(ahi + (size_t)node * DIM + c * 4) = o;
  }
}

// ---------------------------------------------------------------------------
// Weight prep (both layers): Wt[mat][n][k] = bf16(W[k][n])
// ---------------------------------------------------------------------------
__global__ void wprep_kernel(const float* __restrict__ W1l, const float* __restrict__ W1r,
                             const float* __restrict__ W2l, const float* __restrict__ W2r,
                             unsigned short* __restrict__ Wt1, unsigned short* __restrict__ Wt2) {
  int idx = blockIdx.x * 256 + threadIdx.x;  // 65536 total
  int layer = idx >> 15;
  int rest = idx & 32767;
  int mat = rest >> 14;
  int r = rest & 16383;
  int k = r >> 7, n = r & 127;
  const float* W = layer ? (mat ? W2r : W2l) : (mat ? W1r : W1l);
  unsigned short* Wt = layer ? Wt2 : Wt1;
  Wt[((size_t)(mat * 128 + n)) * 128 + k] = f2bf(W[k * 128 + n]);
}

// ---------------------------------------------------------------------------
// Dense via MFMA: out = act(agg_hi @ Wl + bl + (h_hi + h_lo) @ Wr)
// ---------------------------------------------------------------------------
template <bool RELU, bool WPLANES, bool WOUT>
__global__ __launch_bounds__(256, 2) void dense_mfma_kernel(
    const unsigned short* __restrict__ ahi, const unsigned short* __restrict__ hhi,
    const unsigned short* __restrict__ hlo, const unsigned short* __restrict__ Wt,
    const float* __restrict__ bl, float* __restrict__ out,
    unsigned short* __restrict__ phi, unsigned short* __restrict__ plo, int n) {
  const int t = threadIdx.x;
  const int wave = t >> 6, lane = t & 63;
  const int l15 = lane & 15, l4 = lane >> 4;
  const int base = blockIdx.x * 64;

  bf16x8 bfr[2][4][2];
#pragma unroll
  for (int mat = 0; mat < 2; ++mat)
#pragma unroll
    for (int kt = 0; kt < 4; ++kt)
#pragma unroll
      for (int ntl = 0; ntl < 2; ++ntl) {
        int ncol = (wave * 2 + ntl) * 16 + l15;
        int k0 = kt * 32 + l4 * 8;
        bfr[mat][kt][ntl] = *(const bf16x8*)(Wt + ((size_t)(mat * 128 + ncol)) * 128 + k0);
      }

  f32x4 acc[4][2];
#pragma unroll
  for (int ntl = 0; ntl < 2; ++ntl) {
    float b = bl[(wave * 2 + ntl) * 16 + l15];
#pragma unroll
    for (int rt = 0; rt < 4; ++rt) {
      f32x4 ib = {b, b, b, b};
      acc[rt][ntl] = ib;
    }
  }

#pragma unroll
  for (int kt = 0; kt < 4; ++kt) {
    const int k0 = kt * 32 + l4 * 8;
#pragma unroll
    for (int rt = 0; rt < 4; ++rt) {
      int row = base + rt * 16 + l15;
      if (row >= n) row = n - 1;  // clamp: padded rows computed but never stored
      const size_t off = (size_t)row * DIM + k0;
      bf16x8 a8 = *(const bf16x8*)(ahi + off);
      bf16x8 hh8 = *(const bf16x8*)(hhi + off);
      bf16x8 hl8 = *(const bf16x8*)(hlo + off);
#pragma unroll
      for (int ntl = 0; ntl < 2; ++ntl) {
        acc[rt][ntl] = __builtin_amdgcn_mfma_f32_16x16x32_bf16(a8, bfr[0][kt][ntl], acc[rt][ntl], 0, 0, 0);
        acc[rt][ntl] = __builtin_amdgcn_mfma_f32_16x16x32_bf16(hh8, bfr[1][kt][ntl], acc[rt][ntl], 0, 0, 0);
        acc[rt][ntl] = __builtin_amdgcn_mfma_f32_16x16x32_bf16(hl8, bfr[1][kt][ntl], acc[rt][ntl], 0, 0, 0);
      }
    }
  }

  __syncthreads();  // all plane reads complete before in-place plane writes

#pragma unroll
  for (int rt = 0; rt < 4; ++rt)
#pragma unroll
    for (int ntl = 0; ntl < 2; ++ntl) {
      const int col = (wave * 2 + ntl) * 16 + l15;
#pragma unroll
      for (int r = 0; r < 4; ++r) {
        int row = base + rt * 16 + l4 * 4 + r;
        if (row < n) {
          float v = acc[rt][ntl][r];
          if (RELU) v = fmaxf(v, 0.f);
          const size_t off = (size_t)row * DIM + col;
          if (WOUT) out[off] = v;
          if (WPLANES) {
            unsigned short hi = f2bf(v);
            phi[off] = hi;
            plo[off] = f2bf(v - bf2f(hi));
          }
        }
      }
    }
}

// ---------------------------------------------------------------------------
extern "C" void kernel_launch(void* const* d_in, const int* in_sizes, int n_in,
                              void* d_out, int out_size, void* d_ws, size_t ws_size,
                              hipStream_t stream) {
  const float* x   = (const float*)d_in[0];
  const void* edges = d_in[1];
  const float* W1l = (const float*)d_in[2];
  const float* b1l = (const float*)d_in[3];
  const float* W1r = (const float*)d_in[4];
  const float* W2l = (const float*)d_in[5];
  const float* b2l = (const float*)d_in[6];
  const float* W2r = (const float*)d_in[7];
  float* out = (float*)d_out;

  // ---- workspace layout (total ~96.6 MB; partition buffer aliases ahi)
  char* p = (char*)d_ws;
  unsigned short* Wt1 = (unsigned short*)p;               p += 2 * 128 * 128 * 2;
  unsigned short* Wt2 = (unsigned short*)p;               p += 2 * 128 * 128 * 2;
  int* cnt  = (int*)p;                                    p += (size_t)NN * 4;
  int* bcnt = (int*)p;                                    p += (size_t)NB * 4;
  int* novf = (int*)p;                                    p += 4;
  p = (char*)(((uintptr_t)p + 15) & ~(uintptr_t)15);
  int* ovf = (int*)p;                                     p += (size_t)OVF_CAP * 2 * 4;
  p = (char*)(((uintptr_t)p + 255) & ~(uintptr_t)255);
  int* ell = (int*)p;                                     p += (size_t)NB * 512 * CAP * 4;  // padded ELL
  p = (char*)(((uintptr_t)p + 255) & ~(uintptr_t)255);
  unsigned short* hhi = (unsigned short*)p;               p += (size_t)NN * DIM * 2;
  unsigned short* hlo = (unsigned short*)p;               p += (size_t)NN * DIM * 2;
  unsigned short* ahi = (unsigned short*)p;               p += (size_t)NN * DIM * 2;
  unsigned* part = (unsigned*)ahi;  // alias: part dead before first write to ahi

  // zero bcnt + novf in one memset (cnt fully rewritten by partB)
  hipMemsetAsync(bcnt, 0, ((size_t)NB + 1) * 4, stream);

  partA_kernel<<<(EE + ACHUNK - 1) / ACHUNK, ATHREADS, 0, stream>>>(edges, bcnt, part, novf, ovf);
  partB_kernel<<<NB * 2, 256, 0, stream>>>(bcnt, part, cnt, ell, novf, ovf);

  wprep_kernel<<<256, 256, 0, stream>>>(W1l, W1r, W2l, W2r, Wt1, Wt2);
  cast2_kernel<<<(NN * DIM / 4 + 255) / 256, 256, 0, stream>>>(x, hhi, hlo);

  const int gather_blocks = (NN + 3) / 4;
  const int dense_blocks = (NN + 63) / 64;

  // ---- layer 1: h1 = relu(mean_agg(x) @ W1l + b1l + x @ W1r) -> hi/lo planes
  gather_ell_kernel<<<gather_blocks, 256, 0, stream>>>(cnt, ell, hhi, ahi, novf, ovf);
  dense_mfma_kernel<true, true, false><<<dense_blocks, 256, 0, stream>>>(
      ahi, hhi, hlo, Wt1, b1l, out, hhi, hlo, NN);

  // ---- layer 2: out = mean_agg(h1) @ W2l + b2l + h1 @ W2r -> f32 out
  gather_ell_kernel<<<gather_blocks, 256, 0, stream>>>(cnt, ell, hhi, ahi, novf, ovf);
  dense_mfma_kernel<false, false, true><<<dense_blocks, 256, 0, stream>>>(
      ahi, hhi, hlo, Wt2, b2l, out, nullptr, nullptr, NN);
}

// Round 8
// 270.657 us; speedup vs baseline: 2.0472x; 2.0472x over previous
//
#include <hip/hip_runtime.h>
#include <cstdint>
#include <cstddef>

#define NN 100000
#define EE 1600000
#define DIM 128
#define CAP 48        // ELL row capacity (mean deg 16; P(deg>48) ~ 5e-11 per node)
#define OVF_CAP 512   // overflow edge capacity (expected 0 used)

#define NB 391        // dst buckets of 256 nodes: ceil(100000/256)
#define BCAP 4608     // per-bucket partition capacity (mean 4092, +8 sigma)
#define SLOTS 32      // LDS staging slots per bucket
#define FLUSH_AT 16   // flush threshold (entries)
#define ACHUNK 4096   // edges per phase-A block -> 391 blocks (CU coverage)

typedef __attribute__((ext_vector_type(8))) short bf16x8;
typedef __attribute__((ext_vector_type(8))) unsigned short u16x8;
typedef __attribute__((ext_vector_type(4))) float f32x4;

__device__ __forceinline__ unsigned short f2bf(float f) {
  union { float f; uint32_t u; } v; v.f = f;
  uint32_t r = v.u + 0x7FFF + ((v.u >> 16) & 1);  // RNE to bf16
  return (unsigned short)(r >> 16);
}
__device__ __forceinline__ float bf2f(unsigned short s) {
  union { uint32_t u; float f; } v; v.u = (uint32_t)s << 16;
  return v.f;
}

// ---------------------------------------------------------------------------
// Phase A: partition edges into NB dst-buckets with LDS staging.
// pack = s | ((d & 255) << 17)   (s < 2^17)
// Round-6 structure (per-thread serial flush: ~30 flushing threads run their
// atomic+store chains in PARALLEL — round-7's wave-serial flush regressed 3x).
// Fixes vs round 6: stage padded [SLOTS+1] (flush bank = (b*33+i)%32, kills
// the 1.45M same-bank conflicts), ACHUNK 4096 (grid 196->391 blocks).
// ---------------------------------------------------------------------------
__global__ __launch_bounds__(256) void partA_kernel(
    const void* __restrict__ edges, int* __restrict__ bcnt,
    unsigned* __restrict__ part, int* __restrict__ novf, int* __restrict__ ovf) {
  __shared__ unsigned stage[NB][SLOTS + 1];  // +1 pad: de-alias flush banks
  __shared__ int scnt[NB];
  __shared__ int sh_i64;
  const int t = threadIdx.x;
  for (int b = t; b < NB; b += 256) scnt[b] = 0;
  if (t < 64) {
    // int64 little-endian => odd 32-bit words of first 64 entries all zero;
    // int32 => those words are random src values, all-zero impossible.
    int v = ((const int*)edges)[2 * t + 1];
    unsigned long long m = __ballot(v != 0);
    if (t == 0) sh_i64 = (m == 0ull) ? 1 : 0;
  }
  __syncthreads();
  const int i64 = sh_i64;
  const long long ebase = (long long)blockIdx.x * ACHUNK;
  const int nrounds = ACHUNK / 256;
  for (int r = 0; r < nrounds; ++r) {
    long long e = ebase + (long long)r * 256 + t;
    if (e < EE) {
      int s, d;
      if (i64) {
        s = (int)((const long long*)edges)[e];
        d = (int)((const long long*)edges)[(long long)EE + e];
      } else {
        s = ((const int*)edges)[e];
        d = ((const int*)edges)[(long long)EE + e];
      }
      if ((unsigned)s < NN && (unsigned)d < NN) {
        int b = d >> 8;
        unsigned pk = (unsigned)s | ((unsigned)(d & 255) << 17);
        int pos = atomicAdd(&scnt[b], 1);
        if (pos < SLOTS) {
          stage[b][pos] = pk;
        } else {  // stage overflow (rare): direct append
          int g = atomicAdd(&bcnt[b], 1);
          if (g < BCAP) part[(size_t)b * BCAP + g] = pk;
          else { int oi = atomicAdd(novf, 1); if (oi < OVF_CAP) { ovf[oi*2] = s; ovf[oi*2+1] = d; } }
        }
      }
    }
    __syncthreads();
    const bool last = (r == nrounds - 1);
    for (int b = t; b < NB; b += 256) {
      int c = scnt[b];
      if (c > SLOTS) c = SLOTS;
      if (c > 0 && (last || c >= FLUSH_AT)) {
        int g = atomicAdd(&bcnt[b], c);
        for (int i = 0; i < c; ++i) {
          int gp = g + i;
          unsigned pk = stage[b][i];
          if (gp < BCAP) {
            part[(size_t)b * BCAP + gp] = pk;
          } else {
            int oi = atomicAdd(novf, 1);
            if (oi < OVF_CAP) { ovf[oi*2] = (int)(pk & 0x1FFFF); ovf[oi*2+1] = (b << 8) | (int)(pk >> 17); }
          }
        }
        scnt[b] = 0;
      }
    }
    __syncthreads();
  }
}

// ---------------------------------------------------------------------------
// Phase B: per bucket (256 nodes), build ELL rows in LDS (LDS atomics),
// write densely coalesced. Also emits cnt (degree) -- no cnt memset needed.
// ---------------------------------------------------------------------------
__global__ __launch_bounds__(256) void partB_kernel(
    const int* __restrict__ bcnt, const unsigned* __restrict__ part,
    int* __restrict__ cnt, int* __restrict__ ell,
    int* __restrict__ novf, int* __restrict__ ovf) {
  __shared__ int lcnt[256];
  __shared__ int lell[256 * CAP];  // 48 KB
  const int t = threadIdx.x;
  const int b = blockIdx.x;
  lcnt[t] = 0;
  __syncthreads();
  int n = bcnt[b];
  if (n > BCAP) n = BCAP;
  for (int i = t; i < n; i += 256) {
    unsigned pk = part[(size_t)b * BCAP + i];
    int s = (int)(pk & 0x1FFFF);
    int dl = (int)(pk >> 17);
    int pos = atomicAdd(&lcnt[dl], 1);
    if (pos < CAP) lell[dl * CAP + pos] = s;
    else { int oi = atomicAdd(novf, 1); if (oi < OVF_CAP) { ovf[oi*2] = s; ovf[oi*2+1] = (b << 8) | dl; } }
  }
  __syncthreads();
  int4* dst = (int4*)(ell + (size_t)b * 256 * CAP);
  const int4* src = (const int4*)lell;
#pragma unroll
  for (int i = 0; i < 256 * CAP / 4 / 256; ++i) dst[t + i * 256] = src[t + i * 256];
  int node = b * 256 + t;
  if (node < NN) cnt[node] = lcnt[t];
}

// ---------------------------------------------------------------------------
// x (f32) -> bf16 plane (hi only; lo-planes dropped -- error budget analysis:
// activation rounding adds ~0.01-0.02 absmax on top of weight-rounding 0.031)
// ---------------------------------------------------------------------------
__global__ void cast_kernel(const float* __restrict__ x, unsigned short* __restrict__ xhi) {
  int i = blockIdx.x * 256 + threadIdx.x;  // one float4 per thread
  if (i >= NN * DIM / 4) return;
  f32x4 v = ((const f32x4*)x)[i];
  ushort4 hi;
  hi.x = f2bf(v[0]); hi.y = f2bf(v[1]); hi.z = f2bf(v[2]); hi.w = f2bf(v[3]);
  ((ushort4*)xhi)[i] = hi;
}

// ---------------------------------------------------------------------------
// Gather-aggregate from ELL (bf16 plane -> bf16 agg plane).
// One wave per node; QUARTER-wave per neighbor row: lane = q*16 + l,
// lane loads ushort8 (16B) at col l*8; quarters take neighbors q, q+4, ...
// 2-deep unroll -> 8 rows in flight per wave (memory-level parallelism).
// Reduce across quarters via shfl_xor(16|32); quarter 0 writes.
// ---------------------------------------------------------------------------
__global__ __launch_bounds__(256) void gather_ell_kernel(
    const int* __restrict__ cnt, const int* __restrict__ ell,
    const unsigned short* __restrict__ h, unsigned short* __restrict__ ahi,
    const int* __restrict__ novf, const int* __restrict__ ovf) {
  const int node = blockIdx.x * 4 + (threadIdx.x >> 6);
  const int lane = threadIdx.x & 63;
  const int q = lane >> 4;       // quarter 0..3
  const int l = lane & 15;       // lane-in-quarter: cols l*8..l*8+7
  if (node >= NN) return;
  const int dcnt = cnt[node];
  const int n = dcnt < CAP ? dcnt : CAP;
  const int* row = ell + (size_t)node * CAP;
  float s[8] = {0.f, 0.f, 0.f, 0.f, 0.f, 0.f, 0.f, 0.f};
  int p = q;
  for (; p + 4 < n; p += 8) {
    u16x8 v0 = *(const u16x8*)(h + (size_t)row[p] * DIM + l * 8);
    u16x8 v1 = *(const u16x8*)(h + (size_t)row[p + 4] * DIM + l * 8);
#pragma unroll
    for (int i = 0; i < 8; ++i) s[i] += bf2f(v0[i]) + bf2f(v1[i]);
  }
  if (p < n) {
    u16x8 v0 = *(const u16x8*)(h + (size_t)row[p] * DIM + l * 8);
#pragma unroll
    for (int i = 0; i < 8; ++i) s[i] += bf2f(v0[i]);
  }
#pragma unroll
  for (int i = 0; i < 8; ++i) {
    s[i] += __shfl_xor(s[i], 16, 64);
    s[i] += __shfl_xor(s[i], 32, 64);
  }
  if (q == 0) {
    if (dcnt > CAP) {  // overflow fixup: scan tiny list (expected empty)
      int no = *novf;
      if (no > OVF_CAP) no = OVF_CAP;
      for (int i = 0; i < no; ++i) {
        if (ovf[i * 2 + 1] == node) {
          u16x8 v0 = *(const u16x8*)(h + (size_t)ovf[i * 2] * DIM + l * 8);
#pragma unroll
          for (int j = 0; j < 8; ++j) s[j] += bf2f(v0[j]);
        }
      }
    }
    const float rd = 1.0f / fmaxf((float)dcnt, 1.0f);
    u16x8 o;
#pragma unroll
    for (int i = 0; i < 8; ++i) o[i] = f2bf(s[i] * rd);
    *(u16x8*)(ahi + (size_t)node * DIM + l * 8) = o;
  }
}

// ---------------------------------------------------------------------------
// Weight prep (both layers): Wt[mat][n][k] = bf16(W[k][n])
// ---------------------------------------------------------------------------
__global__ void wprep_kernel(const float* __restrict__ W1l, const float* __restrict__ W1r,
                             const float* __restrict__ W2l, const float* __restrict__ W2r,
                             unsigned short* __restrict__ Wt1, unsigned short* __restrict__ Wt2) {
  int idx = blockIdx.x * 256 + threadIdx.x;  // 65536 total
  int layer = idx >> 15;
  int rest = idx & 32767;
  int mat = rest >> 14;
  int r = rest & 16383;
  int k = r >> 7, n = r & 127;
  const float* W = layer ? (mat ? W2r : W2l) : (mat ? W1r : W1l);
  unsigned short* Wt = layer ? Wt2 : Wt1;
  Wt[((size_t)(mat * 128 + n)) * 128 + k] = f2bf(W[k * 128 + n]);
}

// ---------------------------------------------------------------------------
// Dense via MFMA: out = act(agg @ Wl + bl + h @ Wr), all-bf16 inputs.
// 2 loads + 4 MFMAs per (kt,rt) fragment pair. 64 rows x 128 cols per block.
// ---------------------------------------------------------------------------
template <bool RELU, bool WPLANES, bool WOUT>
__global__ __launch_bounds__(256, 2) void dense_mfma_kernel(
    const unsigned short* __restrict__ ahi, const unsigned short* __restrict__ hhi,
    const unsigned short* __restrict__ Wt, const float* __restrict__ bl,
    float* __restrict__ out, unsigned short* __restrict__ phi, int n) {
  const int t = threadIdx.x;
  const int wave = t >> 6, lane = t & 63;
  const int l15 = lane & 15, l4 = lane >> 4;
  const int base = blockIdx.x * 64;

  bf16x8 bfr[2][4][2];
#pragma unroll
  for (int mat = 0; mat < 2; ++mat)
#pragma unroll
    for (int kt = 0; kt < 4; ++kt)
#pragma unroll
      for (int ntl = 0; ntl < 2; ++ntl) {
        int ncol = (wave * 2 + ntl) * 16 + l15;
        int k0 = kt * 32 + l4 * 8;
        bfr[mat][kt][ntl] = *(const bf16x8*)(Wt + ((size_t)(mat * 128 + ncol)) * 128 + k0);
      }

  f32x4 acc[4][2];
#pragma unroll
  for (int ntl = 0; ntl < 2; ++ntl) {
    float b = bl[(wave * 2 + ntl) * 16 + l15];
#pragma unroll
    for (int rt = 0; rt < 4; ++rt) {
      f32x4 ib = {b, b, b, b};
      acc[rt][ntl] = ib;
    }
  }

#pragma unroll
  for (int kt = 0; kt < 4; ++kt) {
    const int k0 = kt * 32 + l4 * 8;
#pragma unroll
    for (int rt = 0; rt < 4; ++rt) {
      int row = base + rt * 16 + l15;
      if (row >= n) row = n - 1;  // clamp: padded rows computed but never stored
      const size_t off = (size_t)row * DIM + k0;
      bf16x8 a8 = *(const bf16x8*)(ahi + off);
      bf16x8 hh8 = *(const bf16x8*)(hhi + off);
#pragma unroll
      for (int ntl = 0; ntl < 2; ++ntl) {
        acc[rt][ntl] = __builtin_amdgcn_mfma_f32_16x16x32_bf16(a8, bfr[0][kt][ntl], acc[rt][ntl], 0, 0, 0);
        acc[rt][ntl] = __builtin_amdgcn_mfma_f32_16x16x32_bf16(hh8, bfr[1][kt][ntl], acc[rt][ntl], 0, 0, 0);
      }
    }
  }

  __syncthreads();  // all plane reads complete before in-place plane writes

#pragma unroll
  for (int rt = 0; rt < 4; ++rt)
#pragma unroll
    for (int ntl = 0; ntl < 2; ++ntl) {
      const int col = (wave * 2 + ntl) * 16 + l15;
#pragma unroll
      for (int r = 0; r < 4; ++r) {
        int row = base + rt * 16 + l4 * 4 + r;
        if (row < n) {
          float v = acc[rt][ntl][r];
          if (RELU) v = fmaxf(v, 0.f);
          const size_t off = (size_t)row * DIM + col;
          if (WOUT) out[off] = v;
          if (WPLANES) phi[off] = f2bf(v);
        }
      }
    }
}

// ---------------------------------------------------------------------------
extern "C" void kernel_launch(void* const* d_in, const int* in_sizes, int n_in,
                              void* d_out, int out_size, void* d_ws, size_t ws_size,
                              hipStream_t stream) {
  const float* x   = (const float*)d_in[0];
  const void* edges = d_in[1];
  const float* W1l = (const float*)d_in[2];
  const float* b1l = (const float*)d_in[3];
  const float* W1r = (const float*)d_in[4];
  const float* W2l = (const float*)d_in[5];
  const float* b2l = (const float*)d_in[6];
  const float* W2r = (const float*)d_in[7];
  float* out = (float*)d_out;

  // ---- workspace layout (~71 MB; partition buffer aliases ahi)
  char* p = (char*)d_ws;
  unsigned short* Wt1 = (unsigned short*)p;               p += 2 * 128 * 128 * 2;
  unsigned short* Wt2 = (unsigned short*)p;               p += 2 * 128 * 128 * 2;
  int* cnt  = (int*)p;                                    p += (size_t)NN * 4;
  int* bcnt = (int*)p;                                    p += (size_t)NB * 4;
  int* novf = (int*)p;                                    p += 4;
  p = (char*)(((uintptr_t)p + 15) & ~(uintptr_t)15);
  int* ovf = (int*)p;                                     p += (size_t)OVF_CAP * 2 * 4;
  p = (char*)(((uintptr_t)p + 255) & ~(uintptr_t)255);
  int* ell = (int*)p;                                     p += (size_t)NB * 256 * CAP * 4;  // padded ELL
  p = (char*)(((uintptr_t)p + 255) & ~(uintptr_t)255);
  unsigned short* hhi = (unsigned short*)p;               p += (size_t)NN * DIM * 2;
  unsigned short* ahi = (unsigned short*)p;               p += (size_t)NN * DIM * 2;
  unsigned* part = (unsigned*)ahi;  // alias: part dead before first write to ahi

  // zero bcnt + novf in one memset (cnt fully rewritten by partB)
  hipMemsetAsync(bcnt, 0, ((size_t)NB + 1) * 4, stream);

  partA_kernel<<<(EE + ACHUNK - 1) / ACHUNK, 256, 0, stream>>>(edges, bcnt, part, novf, ovf);
  partB_kernel<<<NB, 256, 0, stream>>>(bcnt, part, cnt, ell, novf, ovf);

  wprep_kernel<<<256, 256, 0, stream>>>(W1l, W1r, W2l, W2r, Wt1, Wt2);
  cast_kernel<<<(NN * DIM / 4 + 255) / 256, 256, 0, stream>>>(x, hhi);

  const int gather_blocks = (NN + 3) / 4;
  const int dense_blocks = (NN + 63) / 64;

  // ---- layer 1: h1 = relu(mean_agg(x) @ W1l + b1l + x @ W1r) -> bf16 plane
  gather_ell_kernel<<<gather_blocks, 256, 0, stream>>>(cnt, ell, hhi, ahi, novf, ovf);
  dense_mfma_kernel<true, true, false><<<dense_blocks, 256, 0, stream>>>(
      ahi, hhi, Wt1, b1l, out, hhi, NN);

  // ---- layer 2: out = mean_agg(h1) @ W2l + b2l + h1 @ W2r -> f32 out
  gather_ell_kernel<<<gather_blocks, 256, 0, stream>>>(cnt, ell, hhi, ahi, novf, ovf);
  dense_mfma_kernel<false, false, true><<<dense_blocks, 256, 0, stream>>>(
      ahi, hhi, Wt2, b2l, out, nullptr, NN);
}

// Round 9
// 270.584 us; speedup vs baseline: 2.0477x; 1.0003x over previous
//
#include <hip/hip_runtime.h>
#include <cstdint>
#include <cstddef>

#define NN 100000
#define EE 1600000
#define DIM 128
#define CAP 48        // ELL row capacity (mean deg 16; P(deg>48) ~ 5e-11 per node)
#define OVF_CAP 512   // overflow edge capacity (expected 0 used)

#define NB 391        // dst buckets of 256 nodes: ceil(100000/256)
#define BCAP 4608     // per-bucket partition capacity (mean 4092, +8 sigma)
#define SLOTS 32      // LDS staging slots per bucket
#define FLUSH_AT 16   // flush threshold (entries)
#define ACHUNK 4096   // edges per phase-A block -> 391 blocks (CU coverage)

typedef __attribute__((ext_vector_type(8))) short bf16x8;
typedef __attribute__((ext_vector_type(4))) float f32x4;

__device__ __forceinline__ unsigned short f2bf(float f) {
  union { float f; uint32_t u; } v; v.f = f;
  uint32_t r = v.u + 0x7FFF + ((v.u >> 16) & 1);  // RNE to bf16
  return (unsigned short)(r >> 16);
}
__device__ __forceinline__ float bf2f(unsigned short s) {
  union { uint32_t u; float f; } v; v.u = (uint32_t)s << 16;
  return v.f;
}
__device__ __forceinline__ float uaf(uint32_t u) {
  union { uint32_t u; float f; } v; v.u = u;
  return v.f;
}

// ---------------------------------------------------------------------------
// Phase A: partition edges into NB dst-buckets with LDS staging.
// pack = s | ((d & 255) << 17)   (s < 2^17)
// Per-thread serial flush (parallel across ~30 flushing threads; the round-7
// wave-serial flush serialized the atomic->store chains and regressed 3x).
// stage padded [SLOTS+1]: flush reads hit bank (b*33+i)%32 -> no conflicts.
// ---------------------------------------------------------------------------
__global__ __launch_bounds__(256) void partA_kernel(
    const void* __restrict__ edges, int* __restrict__ bcnt,
    unsigned* __restrict__ part, int* __restrict__ novf, int* __restrict__ ovf) {
  __shared__ unsigned stage[NB][SLOTS + 1];  // +1 pad: de-alias flush banks
  __shared__ int scnt[NB];
  __shared__ int sh_i64;
  const int t = threadIdx.x;
  for (int b = t; b < NB; b += 256) scnt[b] = 0;
  if (t < 64) {
    // int64 little-endian => odd 32-bit words of first 64 entries all zero;
    // int32 => those words are random src values, all-zero impossible.
    int v = ((const int*)edges)[2 * t + 1];
    unsigned long long m = __ballot(v != 0);
    if (t == 0) sh_i64 = (m == 0ull) ? 1 : 0;
  }
  __syncthreads();
  const int i64 = sh_i64;
  const long long ebase = (long long)blockIdx.x * ACHUNK;
  const int nrounds = ACHUNK / 256;
  for (int r = 0; r < nrounds; ++r) {
    long long e = ebase + (long long)r * 256 + t;
    if (e < EE) {
      int s, d;
      if (i64) {
        s = (int)((const long long*)edges)[e];
        d = (int)((const long long*)edges)[(long long)EE + e];
      } else {
        s = ((const int*)edges)[e];
        d = ((const int*)edges)[(long long)EE + e];
      }
      if ((unsigned)s < NN && (unsigned)d < NN) {
        int b = d >> 8;
        unsigned pk = (unsigned)s | ((unsigned)(d & 255) << 17);
        int pos = atomicAdd(&scnt[b], 1);
        if (pos < SLOTS) {
          stage[b][pos] = pk;
        } else {  // stage overflow (rare): direct append
          int g = atomicAdd(&bcnt[b], 1);
          if (g < BCAP) part[(size_t)b * BCAP + g] = pk;
          else { int oi = atomicAdd(novf, 1); if (oi < OVF_CAP) { ovf[oi*2] = s; ovf[oi*2+1] = d; } }
        }
      }
    }
    __syncthreads();
    const bool last = (r == nrounds - 1);
    for (int b = t; b < NB; b += 256) {
      int c = scnt[b];
      if (c > SLOTS) c = SLOTS;
      if (c > 0 && (last || c >= FLUSH_AT)) {
        int g = atomicAdd(&bcnt[b], c);
        for (int i = 0; i < c; ++i) {
          int gp = g + i;
          unsigned pk = stage[b][i];
          if (gp < BCAP) {
            part[(size_t)b * BCAP + gp] = pk;
          } else {
            int oi = atomicAdd(novf, 1);
            if (oi < OVF_CAP) { ovf[oi*2] = (int)(pk & 0x1FFFF); ovf[oi*2+1] = (b << 8) | (int)(pk >> 17); }
          }
        }
        scnt[b] = 0;
      }
    }
    __syncthreads();
  }
}

// ---------------------------------------------------------------------------
// Phase B: per bucket (256 nodes), build ELL rows in LDS (LDS atomics),
// write densely coalesced. Also emits cnt (degree) -- no cnt memset needed.
// ---------------------------------------------------------------------------
__global__ __launch_bounds__(256) void partB_kernel(
    const int* __restrict__ bcnt, const unsigned* __restrict__ part,
    int* __restrict__ cnt, int* __restrict__ ell,
    int* __restrict__ novf, int* __restrict__ ovf) {
  __shared__ int lcnt[256];
  __shared__ int lell[256 * CAP];  // 48 KB
  const int t = threadIdx.x;
  const int b = blockIdx.x;
  lcnt[t] = 0;
  __syncthreads();
  int n = bcnt[b];
  if (n > BCAP) n = BCAP;
  for (int i = t; i < n; i += 256) {
    unsigned pk = part[(size_t)b * BCAP + i];
    int s = (int)(pk & 0x1FFFF);
    int dl = (int)(pk >> 17);
    int pos = atomicAdd(&lcnt[dl], 1);
    if (pos < CAP) lell[dl * CAP + pos] = s;
    else { int oi = atomicAdd(novf, 1); if (oi < OVF_CAP) { ovf[oi*2] = s; ovf[oi*2+1] = (b << 8) | dl; } }
  }
  __syncthreads();
  int4* dst = (int4*)(ell + (size_t)b * 256 * CAP);
  const int4* src = (const int4*)lell;
#pragma unroll
  for (int i = 0; i < 256 * CAP / 4 / 256; ++i) dst[t + i * 256] = src[t + i * 256];
  int node = b * 256 + t;
  if (node < NN) cnt[node] = lcnt[t];
}

// ---------------------------------------------------------------------------
// Fused prep: blocks 0..255 transpose+cast weights; blocks 256.. cast x->bf16.
// ---------------------------------------------------------------------------
__global__ void prep_kernel(const float* __restrict__ x,
                            const float* __restrict__ W1l, const float* __restrict__ W1r,
                            const float* __restrict__ W2l, const float* __restrict__ W2r,
                            unsigned short* __restrict__ Wt1, unsigned short* __restrict__ Wt2,
                            unsigned short* __restrict__ xhi) {
  if (blockIdx.x < 256) {
    int idx = blockIdx.x * 256 + threadIdx.x;  // 65536 total
    int layer = idx >> 15;
    int rest = idx & 32767;
    int mat = rest >> 14;
    int r = rest & 16383;
    int k = r >> 7, n = r & 127;
    const float* W = layer ? (mat ? W2r : W2l) : (mat ? W1r : W1l);
    unsigned short* Wt = layer ? Wt2 : Wt1;
    Wt[((size_t)(mat * 128 + n)) * 128 + k] = f2bf(W[k * 128 + n]);
  } else {
    int i = (blockIdx.x - 256) * 256 + threadIdx.x;  // one float4 per thread
    if (i >= NN * DIM / 4) return;
    f32x4 v = ((const f32x4*)x)[i];
    ushort4 hi;
    hi.x = f2bf(v[0]); hi.y = f2bf(v[1]); hi.z = f2bf(v[2]); hi.w = f2bf(v[3]);
    ((ushort4*)xhi)[i] = hi;
  }
}

// ---------------------------------------------------------------------------
// Gather-aggregate from ELL (bf16 plane -> bf16 agg plane).
// One wave per node; quarter-wave per neighbor row (lane = q*16+l, lane owns
// cols l*8..l*8+7 as 4 dwords). 4-deep unroll -> 16 rows in flight per wave.
// Pairwise bf16->f32: lo = w<<16, hi = w&0xFFFF0000 (exact; 2 VALU/elem).
// ---------------------------------------------------------------------------
__device__ __forceinline__ void acc_dw4(float* s, uint4 w) {
  s[0] += uaf(w.x << 16); s[1] += uaf(w.x & 0xFFFF0000u);
  s[2] += uaf(w.y << 16); s[3] += uaf(w.y & 0xFFFF0000u);
  s[4] += uaf(w.z << 16); s[5] += uaf(w.z & 0xFFFF0000u);
  s[6] += uaf(w.w << 16); s[7] += uaf(w.w & 0xFFFF0000u);
}

__global__ __launch_bounds__(256) void gather_ell_kernel(
    const int* __restrict__ cnt, const int* __restrict__ ell,
    const unsigned short* __restrict__ h, unsigned short* __restrict__ ahi,
    const int* __restrict__ novf, const int* __restrict__ ovf) {
  const int node = blockIdx.x * 4 + (threadIdx.x >> 6);
  const int lane = threadIdx.x & 63;
  const int q = lane >> 4;       // quarter 0..3
  const int l = lane & 15;       // lane-in-quarter: cols l*8..l*8+7
  if (node >= NN) return;
  const int dcnt = cnt[node];
  const int n = dcnt < CAP ? dcnt : CAP;
  const int* row = ell + (size_t)node * CAP;
  float s[8] = {0.f, 0.f, 0.f, 0.f, 0.f, 0.f, 0.f, 0.f};
  int p = q;
  for (; p + 12 < n; p += 16) {  // 4 independent row loads in flight
    uint4 w0 = *(const uint4*)(h + (size_t)row[p] * DIM + l * 8);
    uint4 w1 = *(const uint4*)(h + (size_t)row[p + 4] * DIM + l * 8);
    uint4 w2 = *(const uint4*)(h + (size_t)row[p + 8] * DIM + l * 8);
    uint4 w3 = *(const uint4*)(h + (size_t)row[p + 12] * DIM + l * 8);
    acc_dw4(s, w0);
    acc_dw4(s, w1);
    acc_dw4(s, w2);
    acc_dw4(s, w3);
  }
  for (; p < n; p += 4) {
    uint4 w0 = *(const uint4*)(h + (size_t)row[p] * DIM + l * 8);
    acc_dw4(s, w0);
  }
#pragma unroll
  for (int i = 0; i < 8; ++i) {
    s[i] += __shfl_xor(s[i], 16, 64);
    s[i] += __shfl_xor(s[i], 32, 64);
  }
  if (q == 0) {
    if (dcnt > CAP) {  // overflow fixup: scan tiny list (expected empty)
      int no = *novf;
      if (no > OVF_CAP) no = OVF_CAP;
      for (int i = 0; i < no; ++i) {
        if (ovf[i * 2 + 1] == node) {
          uint4 w0 = *(const uint4*)(h + (size_t)ovf[i * 2] * DIM + l * 8);
          acc_dw4(s, w0);
        }
      }
    }
    const float rd = 1.0f / fmaxf((float)dcnt, 1.0f);
    ushort4 o0, o1;
    o0.x = f2bf(s[0] * rd); o0.y = f2bf(s[1] * rd);
    o0.z = f2bf(s[2] * rd); o0.w = f2bf(s[3] * rd);
    o1.x = f2bf(s[4] * rd); o1.y = f2bf(s[5] * rd);
    o1.z = f2bf(s[6] * rd); o1.w = f2bf(s[7] * rd);
    *(ushort4*)(ahi + (size_t)node * DIM + l * 8) = o0;
    *(ushort4*)(ahi + (size_t)node * DIM + l * 8 + 4) = o1;
  }
}

// ---------------------------------------------------------------------------
// Dense via MFMA: out = act(agg @ Wl + bl + h @ Wr), all-bf16 inputs.
// 2 loads + 4 MFMAs per (kt,rt) fragment pair. 64 rows x 128 cols per block.
// ---------------------------------------------------------------------------
template <bool RELU, bool WPLANES, bool WOUT>
__global__ __launch_bounds__(256, 2) void dense_mfma_kernel(
    const unsigned short* __restrict__ ahi, const unsigned short* __restrict__ hhi,
    const unsigned short* __restrict__ Wt, const float* __restrict__ bl,
    float* __restrict__ out, unsigned short* __restrict__ phi, int n) {
  const int t = threadIdx.x;
  const int wave = t >> 6, lane = t & 63;
  const int l15 = lane & 15, l4 = lane >> 4;
  const int base = blockIdx.x * 64;

  bf16x8 bfr[2][4][2];
#pragma unroll
  for (int mat = 0; mat < 2; ++mat)
#pragma unroll
    for (int kt = 0; kt < 4; ++kt)
#pragma unroll
      for (int ntl = 0; ntl < 2; ++ntl) {
        int ncol = (wave * 2 + ntl) * 16 + l15;
        int k0 = kt * 32 + l4 * 8;
        bfr[mat][kt][ntl] = *(const bf16x8*)(Wt + ((size_t)(mat * 128 + ncol)) * 128 + k0);
      }

  f32x4 acc[4][2];
#pragma unroll
  for (int ntl = 0; ntl < 2; ++ntl) {
    float b = bl[(wave * 2 + ntl) * 16 + l15];
#pragma unroll
    for (int rt = 0; rt < 4; ++rt) {
      f32x4 ib = {b, b, b, b};
      acc[rt][ntl] = ib;
    }
  }

#pragma unroll
  for (int kt = 0; kt < 4; ++kt) {
    const int k0 = kt * 32 + l4 * 8;
#pragma unroll
    for (int rt = 0; rt < 4; ++rt) {
      int row = base + rt * 16 + l15;
      if (row >= n) row = n - 1;  // clamp: padded rows computed but never stored
      const size_t off = (size_t)row * DIM + k0;
      bf16x8 a8 = *(const bf16x8*)(ahi + off);
      bf16x8 hh8 = *(const bf16x8*)(hhi + off);
#pragma unroll
      for (int ntl = 0; ntl < 2; ++ntl) {
        acc[rt][ntl] = __builtin_amdgcn_mfma_f32_16x16x32_bf16(a8, bfr[0][kt][ntl], acc[rt][ntl], 0, 0, 0);
        acc[rt][ntl] = __builtin_amdgcn_mfma_f32_16x16x32_bf16(hh8, bfr[1][kt][ntl], acc[rt][ntl], 0, 0, 0);
      }
    }
  }

  __syncthreads();  // all plane reads complete before in-place plane writes

#pragma unroll
  for (int rt = 0; rt < 4; ++rt)
#pragma unroll
    for (int ntl = 0; ntl < 2; ++ntl) {
      const int col = (wave * 2 + ntl) * 16 + l15;
#pragma unroll
      for (int r = 0; r < 4; ++r) {
        int row = base + rt * 16 + l4 * 4 + r;
        if (row < n) {
          float v = acc[rt][ntl][r];
          if (RELU) v = fmaxf(v, 0.f);
          const size_t off = (size_t)row * DIM + col;
          if (WOUT) out[off] = v;
          if (WPLANES) phi[off] = f2bf(v);
        }
      }
    }
}

// ---------------------------------------------------------------------------
extern "C" void kernel_launch(void* const* d_in, const int* in_sizes, int n_in,
                              void* d_out, int out_size, void* d_ws, size_t ws_size,
                              hipStream_t stream) {
  const float* x   = (const float*)d_in[0];
  const void* edges = d_in[1];
  const float* W1l = (const float*)d_in[2];
  const float* b1l = (const float*)d_in[3];
  const float* W1r = (const float*)d_in[4];
  const float* W2l = (const float*)d_in[5];
  const float* b2l = (const float*)d_in[6];
  const float* W2r = (const float*)d_in[7];
  float* out = (float*)d_out;

  // ---- workspace layout (~71 MB; partition buffer aliases ahi)
  char* p = (char*)d_ws;
  unsigned short* Wt1 = (unsigned short*)p;               p += 2 * 128 * 128 * 2;
  unsigned short* Wt2 = (unsigned short*)p;               p += 2 * 128 * 128 * 2;
  int* cnt  = (int*)p;                                    p += (size_t)NN * 4;
  int* bcnt = (int*)p;                                    p += (size_t)NB * 4;
  int* novf = (int*)p;                                    p += 4;
  p = (char*)(((uintptr_t)p + 15) & ~(uintptr_t)15);
  int* ovf = (int*)p;                                     p += (size_t)OVF_CAP * 2 * 4;
  p = (char*)(((uintptr_t)p + 255) & ~(uintptr_t)255);
  int* ell = (int*)p;                                     p += (size_t)NB * 256 * CAP * 4;  // padded ELL
  p = (char*)(((uintptr_t)p + 255) & ~(uintptr_t)255);
  unsigned short* hhi = (unsigned short*)p;               p += (size_t)NN * DIM * 2;
  unsigned short* ahi = (unsigned short*)p;               p += (size_t)NN * DIM * 2;
  unsigned* part = (unsigned*)ahi;  // alias: part dead before first write to ahi

  // zero bcnt + novf in one memset (cnt fully rewritten by partB)
  hipMemsetAsync(bcnt, 0, ((size_t)NB + 1) * 4, stream);

  partA_kernel<<<(EE + ACHUNK - 1) / ACHUNK, 256, 0, stream>>>(edges, bcnt, part, novf, ovf);
  partB_kernel<<<NB, 256, 0, stream>>>(bcnt, part, cnt, ell, novf, ovf);

  prep_kernel<<<256 + NN * DIM / 4 / 256, 256, 0, stream>>>(x, W1l, W1r, W2l, W2r, Wt1, Wt2, hhi);

  const int gather_blocks = (NN + 3) / 4;
  const int dense_blocks = (NN + 63) / 64;

  // ---- layer 1: h1 = relu(mean_agg(x) @ W1l + b1l + x @ W1r) -> bf16 plane
  gather_ell_kernel<<<gather_blocks, 256, 0, stream>>>(cnt, ell, hhi, ahi, novf, ovf);
  dense_mfma_kernel<true, true, false><<<dense_blocks, 256, 0, stream>>>(
      ahi, hhi, Wt1, b1l, out, hhi, NN);

  // ---- layer 2: out = mean_agg(h1) @ W2l + b2l + h1 @ W2r -> f32 out
  gather_ell_kernel<<<gather_blocks, 256, 0, stream>>>(cnt, ell, hhi, ahi, novf, ovf);
  dense_mfma_kernel<false, false, true><<<dense_blocks, 256, 0, stream>>>(
      ahi, hhi, Wt2, b2l, out, nullptr, NN);
}

// Round 10
// 270.034 us; speedup vs baseline: 2.0519x; 1.0020x over previous
//
#include <hip/hip_runtime.h>
#include <cstdint>
#include <cstddef>

#define NN 100000
#define EE 1600000
#define DIM 128
#define CAP 48        // ELL row capacity (mean deg 16; P(deg>48) ~ 5e-11 per node)
#define OVF_CAP 512   // overflow edge capacity (expected 0 used)

#define NB 391        // dst buckets of 256 nodes: ceil(100000/256)
#define BCAP 4608     // per-bucket partition capacity (mean 4092, +8 sigma)
#define SLOTS 32      // LDS staging slots per bucket
#define FLUSH_AT 16   // flush threshold (entries)
#define ACHUNK 4096   // edges per phase-A block -> 391 blocks (CU coverage)

typedef __attribute__((ext_vector_type(8))) short bf16x8;
typedef __attribute__((ext_vector_type(4))) float f32x4;

__device__ __forceinline__ unsigned short f2bf(float f) {
  union { float f; uint32_t u; } v; v.f = f;
  uint32_t r = v.u + 0x7FFF + ((v.u >> 16) & 1);  // RNE to bf16
  return (unsigned short)(r >> 16);
}
__device__ __forceinline__ float bf2f(unsigned short s) {
  union { uint32_t u; float f; } v; v.u = (uint32_t)s << 16;
  return v.f;
}
__device__ __forceinline__ float uaf(uint32_t u) {
  union { uint32_t u; float f; } v; v.u = u;
  return v.f;
}

// ---------------------------------------------------------------------------
// Phase A: partition edges into NB dst-buckets with LDS staging.
// pack = s | ((d & 255) << 17)   (s < 2^17)
// Per-thread serial flush (parallel across ~30 flushing threads; the round-7
// wave-serial flush serialized the atomic->store chains and regressed 3x).
// stage padded [SLOTS+1]: flush reads hit bank (b*33+i)%32 -> no conflicts.
// ---------------------------------------------------------------------------
__global__ __launch_bounds__(256) void partA_kernel(
    const void* __restrict__ edges, int* __restrict__ bcnt,
    unsigned* __restrict__ part, int* __restrict__ novf, int* __restrict__ ovf) {
  __shared__ unsigned stage[NB][SLOTS + 1];  // +1 pad: de-alias flush banks
  __shared__ int scnt[NB];
  __shared__ int sh_i64;
  const int t = threadIdx.x;
  for (int b = t; b < NB; b += 256) scnt[b] = 0;
  if (t < 64) {
    // int64 little-endian => odd 32-bit words of first 64 entries all zero;
    // int32 => those words are random src values, all-zero impossible.
    int v = ((const int*)edges)[2 * t + 1];
    unsigned long long m = __ballot(v != 0);
    if (t == 0) sh_i64 = (m == 0ull) ? 1 : 0;
  }
  __syncthreads();
  const int i64 = sh_i64;
  const long long ebase = (long long)blockIdx.x * ACHUNK;
  const int nrounds = ACHUNK / 256;
  for (int r = 0; r < nrounds; ++r) {
    long long e = ebase + (long long)r * 256 + t;
    if (e < EE) {
      int s, d;
      if (i64) {
        s = (int)((const long long*)edges)[e];
        d = (int)((const long long*)edges)[(long long)EE + e];
      } else {
        s = ((const int*)edges)[e];
        d = ((const int*)edges)[(long long)EE + e];
      }
      if ((unsigned)s < NN && (unsigned)d < NN) {
        int b = d >> 8;
        unsigned pk = (unsigned)s | ((unsigned)(d & 255) << 17);
        int pos = atomicAdd(&scnt[b], 1);
        if (pos < SLOTS) {
          stage[b][pos] = pk;
        } else {  // stage overflow (rare): direct append
          int g = atomicAdd(&bcnt[b], 1);
          if (g < BCAP) part[(size_t)b * BCAP + g] = pk;
          else { int oi = atomicAdd(novf, 1); if (oi < OVF_CAP) { ovf[oi*2] = s; ovf[oi*2+1] = d; } }
        }
      }
    }
    __syncthreads();
    const bool last = (r == nrounds - 1);
    for (int b = t; b < NB; b += 256) {
      int c = scnt[b];
      if (c > SLOTS) c = SLOTS;
      if (c > 0 && (last || c >= FLUSH_AT)) {
        int g = atomicAdd(&bcnt[b], c);
        for (int i = 0; i < c; ++i) {
          int gp = g + i;
          unsigned pk = stage[b][i];
          if (gp < BCAP) {
            part[(size_t)b * BCAP + gp] = pk;
          } else {
            int oi = atomicAdd(novf, 1);
            if (oi < OVF_CAP) { ovf[oi*2] = (int)(pk & 0x1FFFF); ovf[oi*2+1] = (b << 8) | (int)(pk >> 17); }
          }
        }
        scnt[b] = 0;
      }
    }
    __syncthreads();
  }
}

// ---------------------------------------------------------------------------
// Phase B: per bucket (256 nodes), build ELL rows in LDS (LDS atomics),
// write densely coalesced. Also emits cnt (degree) -- no cnt memset needed.
// ---------------------------------------------------------------------------
__global__ __launch_bounds__(256) void partB_kernel(
    const int* __restrict__ bcnt, const unsigned* __restrict__ part,
    int* __restrict__ cnt, int* __restrict__ ell,
    int* __restrict__ novf, int* __restrict__ ovf) {
  __shared__ int lcnt[256];
  __shared__ int lell[256 * CAP];  // 48 KB
  const int t = threadIdx.x;
  const int b = blockIdx.x;
  lcnt[t] = 0;
  __syncthreads();
  int n = bcnt[b];
  if (n > BCAP) n = BCAP;
  for (int i = t; i < n; i += 256) {
    unsigned pk = part[(size_t)b * BCAP + i];
    int s = (int)(pk & 0x1FFFF);
    int dl = (int)(pk >> 17);
    int pos = atomicAdd(&lcnt[dl], 1);
    if (pos < CAP) lell[dl * CAP + pos] = s;
    else { int oi = atomicAdd(novf, 1); if (oi < OVF_CAP) { ovf[oi*2] = s; ovf[oi*2+1] = (b << 8) | dl; } }
  }
  __syncthreads();
  int4* dst = (int4*)(ell + (size_t)b * 256 * CAP);
  const int4* src = (const int4*)lell;
#pragma unroll
  for (int i = 0; i < 256 * CAP / 4 / 256; ++i) dst[t + i * 256] = src[t + i * 256];
  int node = b * 256 + t;
  if (node < NN) cnt[node] = lcnt[t];
}

// ---------------------------------------------------------------------------
// Fused prep: blocks 0..255 transpose+cast weights; blocks 256.. cast x->bf16.
// ---------------------------------------------------------------------------
__global__ void prep_kernel(const float* __restrict__ x,
                            const float* __restrict__ W1l, const float* __restrict__ W1r,
                            const float* __restrict__ W2l, const float* __restrict__ W2r,
                            unsigned short* __restrict__ Wt1, unsigned short* __restrict__ Wt2,
                            unsigned short* __restrict__ xhi) {
  if (blockIdx.x < 256) {
    int idx = blockIdx.x * 256 + threadIdx.x;  // 65536 total
    int layer = idx >> 15;
    int rest = idx & 32767;
    int mat = rest >> 14;
    int r = rest & 16383;
    int k = r >> 7, n = r & 127;
    const float* W = layer ? (mat ? W2r : W2l) : (mat ? W1r : W1l);
    unsigned short* Wt = layer ? Wt2 : Wt1;
    Wt[((size_t)(mat * 128 + n)) * 128 + k] = f2bf(W[k * 128 + n]);
  } else {
    int i = (blockIdx.x - 256) * 256 + threadIdx.x;  // one float4 per thread
    if (i >= NN * DIM / 4) return;
    f32x4 v = ((const f32x4*)x)[i];
    ushort4 hi;
    hi.x = f2bf(v[0]); hi.y = f2bf(v[1]); hi.z = f2bf(v[2]); hi.w = f2bf(v[3]);
    ((ushort4*)xhi)[i] = hi;
  }
}

// ---------------------------------------------------------------------------
// Gather-aggregate from ELL (bf16 plane -> bf16 agg plane).
// One wave per node; quarter-wave per neighbor row (lane = q*16+l, lane owns
// cols l*8..l*8+7 as 4 dwords). 4-deep unroll -> 16 rows in flight per wave.
// Pairwise bf16->f32: lo = w<<16, hi = w&0xFFFF0000 (exact; 2 VALU/elem).
// ---------------------------------------------------------------------------
__device__ __forceinline__ void acc_dw4(float* s, uint4 w) {
  s[0] += uaf(w.x << 16); s[1] += uaf(w.x & 0xFFFF0000u);
  s[2] += uaf(w.y << 16); s[3] += uaf(w.y & 0xFFFF0000u);
  s[4] += uaf(w.z << 16); s[5] += uaf(w.z & 0xFFFF0000u);
  s[6] += uaf(w.w << 16); s[7] += uaf(w.w & 0xFFFF0000u);
}

__global__ __launch_bounds__(256) void gather_ell_kernel(
    const int* __restrict__ cnt, const int* __restrict__ ell,
    const unsigned short* __restrict__ h, unsigned short* __restrict__ ahi,
    const int* __restrict__ novf, const int* __restrict__ ovf) {
  const int node = blockIdx.x * 4 + (threadIdx.x >> 6);
  const int lane = threadIdx.x & 63;
  const int q = lane >> 4;       // quarter 0..3
  const int l = lane & 15;       // lane-in-quarter: cols l*8..l*8+7
  if (node >= NN) return;
  const int dcnt = cnt[node];
  const int n = dcnt < CAP ? dcnt : CAP;
  const int* row = ell + (size_t)node * CAP;
  float s[8] = {0.f, 0.f, 0.f, 0.f, 0.f, 0.f, 0.f, 0.f};
  int p = q;
  for (; p + 12 < n; p += 16) {  // 4 independent row loads in flight
    uint4 w0 = *(const uint4*)(h + (size_t)row[p] * DIM + l * 8);
    uint4 w1 = *(const uint4*)(h + (size_t)row[p + 4] * DIM + l * 8);
    uint4 w2 = *(const uint4*)(h + (size_t)row[p + 8] * DIM + l * 8);
    uint4 w3 = *(const uint4*)(h + (size_t)row[p + 12] * DIM + l * 8);
    acc_dw4(s, w0);
    acc_dw4(s, w1);
    acc_dw4(s, w2);
    acc_dw4(s, w3);
  }
  for (; p < n; p += 4) {
    uint4 w0 = *(const uint4*)(h + (size_t)row[p] * DIM + l * 8);
    acc_dw4(s, w0);
  }
#pragma unroll
  for (int i = 0; i < 8; ++i) {
    s[i] += __shfl_xor(s[i], 16, 64);
    s[i] += __shfl_xor(s[i], 32, 64);
  }
  if (q == 0) {
    if (dcnt > CAP) {  // overflow fixup: scan tiny list (expected empty)
      int no = *novf;
      if (no > OVF_CAP) no = OVF_CAP;
      for (int i = 0; i < no; ++i) {
        if (ovf[i * 2 + 1] == node) {
          uint4 w0 = *(const uint4*)(h + (size_t)ovf[i * 2] * DIM + l * 8);
          acc_dw4(s, w0);
        }
      }
    }
    const float rd = 1.0f / fmaxf((float)dcnt, 1.0f);
    ushort4 o0, o1;
    o0.x = f2bf(s[0] * rd); o0.y = f2bf(s[1] * rd);
    o0.z = f2bf(s[2] * rd); o0.w = f2bf(s[3] * rd);
    o1.x = f2bf(s[4] * rd); o1.y = f2bf(s[5] * rd);
    o1.z = f2bf(s[6] * rd); o1.w = f2bf(s[7] * rd);
    *(ushort4*)(ahi + (size_t)node * DIM + l * 8) = o0;
    *(ushort4*)(ahi + (size_t)node * DIM + l * 8 + 4) = o1;
  }
}

// ---------------------------------------------------------------------------
// Dense via MFMA: out = act(agg @ Wl + bl + h @ Wr), all-bf16 inputs.
// 2 loads + 4 MFMAs per (kt,rt) fragment pair. 64 rows x 128 cols per block.
// ---------------------------------------------------------------------------
template <bool RELU, bool WPLANES, bool WOUT>
__global__ __launch_bounds__(256, 2) void dense_mfma_kernel(
    const unsigned short* __restrict__ ahi, const unsigned short* __restrict__ hhi,
    const unsigned short* __restrict__ Wt, const float* __restrict__ bl,
    float* __restrict__ out, unsigned short* __restrict__ phi, int n) {
  const int t = threadIdx.x;
  const int wave = t >> 6, lane = t & 63;
  const int l15 = lane & 15, l4 = lane >> 4;
  const int base = blockIdx.x * 64;

  bf16x8 bfr[2][4][2];
#pragma unroll
  for (int mat = 0; mat < 2; ++mat)
#pragma unroll
    for (int kt = 0; kt < 4; ++kt)
#pragma unroll
      for (int ntl = 0; ntl < 2; ++ntl) {
        int ncol = (wave * 2 + ntl) * 16 + l15;
        int k0 = kt * 32 + l4 * 8;
        bfr[mat][kt][ntl] = *(const bf16x8*)(Wt + ((size_t)(mat * 128 + ncol)) * 128 + k0);
      }

  f32x4 acc[4][2];
#pragma unroll
  for (int ntl = 0; ntl < 2; ++ntl) {
    float b = bl[(wave * 2 + ntl) * 16 + l15];
#pragma unroll
    for (int rt = 0; rt < 4; ++rt) {
      f32x4 ib = {b, b, b, b};
      acc[rt][ntl] = ib;
    }
  }

#pragma unroll
  for (int kt = 0; kt < 4; ++kt) {
    const int k0 = kt * 32 + l4 * 8;
#pragma unroll
    for (int rt = 0; rt < 4; ++rt) {
      int row = base + rt * 16 + l15;
      if (row >= n) row = n - 1;  // clamp: padded rows computed but never stored
      const size_t off = (size_t)row * DIM + k0;
      bf16x8 a8 = *(const bf16x8*)(ahi + off);
      bf16x8 hh8 = *(const bf16x8*)(hhi + off);
#pragma unroll
      for (int ntl = 0; ntl < 2; ++ntl) {
        acc[rt][ntl] = __builtin_amdgcn_mfma_f32_16x16x32_bf16(a8, bfr[0][kt][ntl], acc[rt][ntl], 0, 0, 0);
        acc[rt][ntl] = __builtin_amdgcn_mfma_f32_16x16x32_bf16(hh8, bfr[1][kt][ntl], acc[rt][ntl], 0, 0, 0);
      }
    }
  }

  __syncthreads();  // all plane reads complete before in-place plane writes

#pragma unroll
  for (int rt = 0; rt < 4; ++rt)
#pragma unroll
    for (int ntl = 0; ntl < 2; ++ntl) {
      const int col = (wave * 2 + ntl) * 16 + l15;
#pragma unroll
      for (int r = 0; r < 4; ++r) {
        int row = base + rt * 16 + l4 * 4 + r;
        if (row < n) {
          float v = acc[rt][ntl][r];
          if (RELU) v = fmaxf(v, 0.f);
          const size_t off = (size_t)row * DIM + col;
          if (WOUT) out[off] = v;
          if (WPLANES) phi[off] = f2bf(v);
        }
      }
    }
}

// ---------------------------------------------------------------------------
extern "C" void kernel_launch(void* const* d_in, const int* in_sizes, int n_in,
                              void* d_out, int out_size, void* d_ws, size_t ws_size,
                              hipStream_t stream) {
  const float* x   = (const float*)d_in[0];
  const void* edges = d_in[1];
  const float* W1l = (const float*)d_in[2];
  const float* b1l = (const float*)d_in[3];
  const float* W1r = (const float*)d_in[4];
  const float* W2l = (const float*)d_in[5];
  const float* b2l = (const float*)d_in[6];
  const float* W2r = (const float*)d_in[7];
  float* out = (float*)d_out;

  // ---- workspace layout (~71 MB; partition buffer aliases ahi)
  char* p = (char*)d_ws;
  unsigned short* Wt1 = (unsigned short*)p;               p += 2 * 128 * 128 * 2;
  unsigned short* Wt2 = (unsigned short*)p;               p += 2 * 128 * 128 * 2;
  int* cnt  = (int*)p;                                    p += (size_t)NN * 4;
  int* bcnt = (int*)p;                                    p += (size_t)NB * 4;
  int* novf = (int*)p;                                    p += 4;
  p = (char*)(((uintptr_t)p + 15) & ~(uintptr_t)15);
  int* ovf = (int*)p;                                     p += (size_t)OVF_CAP * 2 * 4;
  p = (char*)(((uintptr_t)p + 255) & ~(uintptr_t)255);
  int* ell = (int*)p;                                     p += (size_t)NB * 256 * CAP * 4;  // padded ELL
  p = (char*)(((uintptr_t)p + 255) & ~(uintptr_t)255);
  unsigned short* hhi = (unsigned short*)p;               p += (size_t)NN * DIM * 2;
  unsigned short* ahi = (unsigned short*)p;               p += (size_t)NN * DIM * 2;
  unsigned* part = (unsigned*)ahi;  // alias: part dead before first write to ahi

  // zero bcnt + novf in one memset (cnt fully rewritten by partB)
  hipMemsetAsync(bcnt, 0, ((size_t)NB + 1) * 4, stream);

  partA_kernel<<<(EE + ACHUNK - 1) / ACHUNK, 256, 0, stream>>>(edges, bcnt, part, novf, ovf);
  partB_kernel<<<NB, 256, 0, stream>>>(bcnt, part, cnt, ell, novf, ovf);

  prep_kernel<<<256 + NN * DIM / 4 / 256, 256, 0, stream>>>(x, W1l, W1r, W2l, W2r, Wt1, Wt2, hhi);

  const int gather_blocks = (NN + 3) / 4;
  const int dense_blocks = (NN + 63) / 64;

  // ---- layer 1: h1 = relu(mean_agg(x) @ W1l + b1l + x @ W1r) -> bf16 plane
  gather_ell_kernel<<<gather_blocks, 256, 0, stream>>>(cnt, ell, hhi, ahi, novf, ovf);
  dense_mfma_kernel<true, true, false><<<dense_blocks, 256, 0, stream>>>(
      ahi, hhi, Wt1, b1l, out, hhi, NN);

  // ---- layer 2: out = mean_agg(h1) @ W2l + b2l + h1 @ W2r -> f32 out
  gather_ell_kernel<<<gather_blocks, 256, 0, stream>>>(cnt, ell, hhi, ahi, novf, ovf);
  dense_mfma_kernel<false, false, true><<<dense_blocks, 256, 0, stream>>>(
      ahi, hhi, Wt2, b2l, out, nullptr, NN);
}

// Round 11
// 268.457 us; speedup vs baseline: 2.0640x; 1.0059x over previous
//
#include <hip/hip_runtime.h>
#include <cstdint>
#include <cstddef>

#define NN 100000
#define EE 1600000
#define DIM 128
#define CAP 48        // ELL row capacity (mean deg 16; P(deg>48) ~ 5e-11 per node)
#define OVF_CAP 512   // overflow edge capacity (expected 0 used)

#define NB 391        // dst buckets of 256 nodes: ceil(100000/256)
#define BCAP 4608     // per-bucket partition capacity (mean 4092, +8 sigma)
#define SLOTS 32      // LDS staging slots per bucket
#define FLUSH_AT 16   // flush threshold (entries)
#define ACHUNK 4096   // edges per phase-A block -> 391 partition blocks
#define ATHREADS 512

#define NPREP_W 128                          // weight-prep blocks (65536/512)
#define NPREP_X ((NN * DIM / 4) / ATHREADS)  // x-cast blocks (6250)

typedef __attribute__((ext_vector_type(8))) short bf16x8;
typedef __attribute__((ext_vector_type(4))) float f32x4;

__device__ __forceinline__ unsigned short f2bf(float f) {
  union { float f; uint32_t u; } v; v.f = f;
  uint32_t r = v.u + 0x7FFF + ((v.u >> 16) & 1);  // RNE to bf16
  return (unsigned short)(r >> 16);
}
__device__ __forceinline__ float uaf(uint32_t u) {
  union { uint32_t u; float f; } v; v.u = u;
  return v.f;
}
__device__ __forceinline__ uint32_t pk2(float a, float b) {
  return (uint32_t)f2bf(a) | ((uint32_t)f2bf(b) << 16);
}
// pairwise bf16->f32 extraction: lo = w<<16, hi = w&0xFFFF0000 (exact)
__device__ __forceinline__ void acc_dw4(float* s, uint4 w) {
  s[0] += uaf(w.x << 16); s[1] += uaf(w.x & 0xFFFF0000u);
  s[2] += uaf(w.y << 16); s[3] += uaf(w.y & 0xFFFF0000u);
  s[4] += uaf(w.z << 16); s[5] += uaf(w.z & 0xFFFF0000u);
  s[6] += uaf(w.w << 16); s[7] += uaf(w.w & 0xFFFF0000u);
}

// ---------------------------------------------------------------------------
// partA_prep: blocks < NB partition edges into dst-buckets (LDS staging,
// per-thread flush); blocks >= NB do independent prep work (weight transpose+
// cast, x->bf16 cast) -- fills CUs that partA leaves idle (partA is LDS-bound
// at ~3 blocks/CU and only 391 blocks).
// pack = s | ((d & 255) << 17)   (s < 2^17)
// ---------------------------------------------------------------------------
__global__ __launch_bounds__(ATHREADS) void partA_prep_kernel(
    const void* __restrict__ edges, int* __restrict__ bcnt,
    unsigned* __restrict__ part, int* __restrict__ novf, int* __restrict__ ovf,
    const float* __restrict__ x,
    const float* __restrict__ W1l, const float* __restrict__ W1r,
    const float* __restrict__ W2l, const float* __restrict__ W2r,
    unsigned short* __restrict__ Wt1, unsigned short* __restrict__ Wt2,
    unsigned short* __restrict__ xhi) {
  __shared__ unsigned stage[NB][SLOTS + 1];  // +1 pad: de-alias flush banks
  __shared__ int scnt[NB];
  __shared__ int sh_i64;
  const int t = threadIdx.x;

  if (blockIdx.x >= NB) {  // ---- prep path (no LDS use) ----
    int bid = blockIdx.x - NB;
    if (bid < NPREP_W) {
      int idx = bid * ATHREADS + t;  // 65536 total
      int layer = idx >> 15;
      int rest = idx & 32767;
      int mat = rest >> 14;
      int r = rest & 16383;
      int k = r >> 7, n = r & 127;
      const float* W = layer ? (mat ? W2r : W2l) : (mat ? W1r : W1l);
      unsigned short* Wt = layer ? Wt2 : Wt1;
      Wt[((size_t)(mat * 128 + n)) * 128 + k] = f2bf(W[k * 128 + n]);
    } else {
      int i = (bid - NPREP_W) * ATHREADS + t;  // one float4 per thread
      if (i < NN * DIM / 4) {
        f32x4 v = ((const f32x4*)x)[i];
        ushort4 hi;
        hi.x = f2bf(v[0]); hi.y = f2bf(v[1]); hi.z = f2bf(v[2]); hi.w = f2bf(v[3]);
        ((ushort4*)xhi)[i] = hi;
      }
    }
    return;
  }

  // ---- partition path ----
  for (int b = t; b < NB; b += ATHREADS) scnt[b] = 0;
  if (t < 64) {
    // int64 little-endian => odd 32-bit words of first 64 entries all zero;
    // int32 => those words are random src values, all-zero impossible.
    int v = ((const int*)edges)[2 * t + 1];
    unsigned long long m = __ballot(v != 0);
    if (t == 0) sh_i64 = (m == 0ull) ? 1 : 0;
  }
  __syncthreads();
  const int i64 = sh_i64;
  const long long ebase = (long long)blockIdx.x * ACHUNK;
  const int nrounds = ACHUNK / ATHREADS;
  for (int r = 0; r < nrounds; ++r) {
    long long e = ebase + (long long)r * ATHREADS + t;
    if (e < EE) {
      int s, d;
      if (i64) {
        s = (int)((const long long*)edges)[e];
        d = (int)((const long long*)edges)[(long long)EE + e];
      } else {
        s = ((const int*)edges)[e];
        d = ((const int*)edges)[(long long)EE + e];
      }
      if ((unsigned)s < NN && (unsigned)d < NN) {
        int b = d >> 8;
        unsigned pk = (unsigned)s | ((unsigned)(d & 255) << 17);
        int pos = atomicAdd(&scnt[b], 1);
        if (pos < SLOTS) {
          stage[b][pos] = pk;
        } else {  // stage overflow (rare): direct append
          int g = atomicAdd(&bcnt[b], 1);
          if (g < BCAP) part[(size_t)b * BCAP + g] = pk;
          else { int oi = atomicAdd(novf, 1); if (oi < OVF_CAP) { ovf[oi*2] = s; ovf[oi*2+1] = d; } }
        }
      }
    }
    __syncthreads();
    const bool last = (r == nrounds - 1);
    for (int b = t; b < NB; b += ATHREADS) {  // per-thread flush (parallel chains)
      int c = scnt[b];
      if (c > SLOTS) c = SLOTS;
      if (c > 0 && (last || c >= FLUSH_AT)) {
        int g = atomicAdd(&bcnt[b], c);
        for (int i = 0; i < c; ++i) {
          int gp = g + i;
          unsigned pk = stage[b][i];
          if (gp < BCAP) {
            part[(size_t)b * BCAP + gp] = pk;
          } else {
            int oi = atomicAdd(novf, 1);
            if (oi < OVF_CAP) { ovf[oi*2] = (int)(pk & 0x1FFFF); ovf[oi*2+1] = (b << 8) | (int)(pk >> 17); }
          }
        }
        scnt[b] = 0;
      }
    }
    __syncthreads();
  }
}

// ---------------------------------------------------------------------------
// Phase B: per bucket (256 nodes), build ELL rows in LDS (LDS atomics),
// write densely coalesced. Also emits cnt (degree) -- no cnt memset needed.
// ---------------------------------------------------------------------------
__global__ __launch_bounds__(256) void partB_kernel(
    const int* __restrict__ bcnt, const unsigned* __restrict__ part,
    int* __restrict__ cnt, int* __restrict__ ell,
    int* __restrict__ novf, int* __restrict__ ovf) {
  __shared__ int lcnt[256];
  __shared__ int lell[256 * CAP];  // 48 KB
  const int t = threadIdx.x;
  const int b = blockIdx.x;
  lcnt[t] = 0;
  __syncthreads();
  int n = bcnt[b];
  if (n > BCAP) n = BCAP;
  for (int i = t; i < n; i += 256) {
    unsigned pk = part[(size_t)b * BCAP + i];
    int s = (int)(pk & 0x1FFFF);
    int dl = (int)(pk >> 17);
    int pos = atomicAdd(&lcnt[dl], 1);
    if (pos < CAP) lell[dl * CAP + pos] = s;
    else { int oi = atomicAdd(novf, 1); if (oi < OVF_CAP) { ovf[oi*2] = s; ovf[oi*2+1] = (b << 8) | dl; } }
  }
  __syncthreads();
  int4* dst = (int4*)(ell + (size_t)b * 256 * CAP);
  const int4* src = (const int4*)lell;
#pragma unroll
  for (int i = 0; i < 256 * CAP / 4 / 256; ++i) dst[t + i * 256] = src[t + i * 256];
  int node = b * 256 + t;
  if (node < NN) cnt[node] = lcnt[t];
}

// ---------------------------------------------------------------------------
// Fused gather+dense: per block of 64 nodes --
//   phase 1: gather mean-agg of the block's nodes from ELL (random bf16 row
//            reads, quarter-wave per row, 2 nodes x 4-deep in flight) into a
//            swizzled LDS tile (64 x 128 bf16, chunk = c16 ^ (row&15) -> <=2-way
//            bank aliasing on both the write and the ds_read_b128).
//   phase 2: dense MFMA out = act(aggLDS @ Wl + bl + h @ Wr); weights loaded
//            per-kt (L2-hot) to keep VGPR low for phase-1 occupancy.
// Deletes the 51 MB/layer agg round-trip through global.
// ---------------------------------------------------------------------------
template <bool RELU, bool WPLANES, bool WOUT>
__global__ __launch_bounds__(256, 3) void fused_kernel(
    const int* __restrict__ cnt, const int* __restrict__ ell,
    const unsigned short* __restrict__ h, const unsigned short* __restrict__ Wt,
    const float* __restrict__ bl, float* __restrict__ out,
    unsigned short* __restrict__ ph,
    const int* __restrict__ novf, const int* __restrict__ ovf) {
  __shared__ unsigned short lds_a[64 * DIM];  // 16 KB, swizzled 16B chunks
  const int t = threadIdx.x;
  const int wave = t >> 6, lane = t & 63;
  const int q = lane >> 4;   // quarter 0..3
  const int l = lane & 15;   // lane-in-quarter: cols l*8..l*8+7
  const int base = blockIdx.x * 64;

  // ---- phase 1: each wave gathers 16 nodes, 2 concurrently ----
  for (int i = 0; i < 16; i += 2) {
    const int nl0 = wave * 16 + i;
    const int nl1 = nl0 + 1;
    const int node0 = base + nl0, node1 = base + nl1;
    const int dc0 = (node0 < NN) ? cnt[node0] : 0;
    const int dc1 = (node1 < NN) ? cnt[node1] : 0;
    const int n0 = dc0 < CAP ? dc0 : CAP;
    const int n1 = dc1 < CAP ? dc1 : CAP;
    const int* r0 = ell + (size_t)node0 * CAP;
    const int* r1 = ell + (size_t)node1 * CAP;
    float s0[8] = {0.f,0.f,0.f,0.f,0.f,0.f,0.f,0.f};
    float s1[8] = {0.f,0.f,0.f,0.f,0.f,0.f,0.f,0.f};
    const int nmax = n0 > n1 ? n0 : n1;
    for (int p = q; p < nmax; p += 16) {  // 8 independent row loads in flight
      uint4 w[8];
#pragma unroll
      for (int j = 0; j < 4; ++j)
        if (p + j * 4 < n0) w[j] = *(const uint4*)(h + (size_t)r0[p + j * 4] * DIM + l * 8);
#pragma unroll
      for (int j = 0; j < 4; ++j)
        if (p + j * 4 < n1) w[4 + j] = *(const uint4*)(h + (size_t)r1[p + j * 4] * DIM + l * 8);
#pragma unroll
      for (int j = 0; j < 4; ++j)
        if (p + j * 4 < n0) acc_dw4(s0, w[j]);
#pragma unroll
      for (int j = 0; j < 4; ++j)
        if (p + j * 4 < n1) acc_dw4(s1, w[4 + j]);
    }
#pragma unroll
    for (int k = 0; k < 8; ++k) {
      s0[k] += __shfl_xor(s0[k], 16, 64);
      s0[k] += __shfl_xor(s0[k], 32, 64);
      s1[k] += __shfl_xor(s1[k], 16, 64);
      s1[k] += __shfl_xor(s1[k], 32, 64);
    }
    if (q == 0) {
      // overflow fixup (expected-empty list scan)
      if (dc0 > CAP || dc1 > CAP) {
        int no = *novf;
        if (no > OVF_CAP) no = OVF_CAP;
        for (int k = 0; k < no; ++k) {
          int od = ovf[k * 2 + 1];
          if (od == node0 && dc0 > CAP) {
            uint4 w = *(const uint4*)(h + (size_t)ovf[k * 2] * DIM + l * 8);
            acc_dw4(s0, w);
          }
          if (od == node1 && dc1 > CAP) {
            uint4 w = *(const uint4*)(h + (size_t)ovf[k * 2] * DIM + l * 8);
            acc_dw4(s1, w);
          }
        }
      }
      const float rd0 = 1.0f / fmaxf((float)dc0, 1.0f);
      const float rd1 = 1.0f / fmaxf((float)dc1, 1.0f);
      uint4 pk0, pk1;
      pk0.x = pk2(s0[0]*rd0, s0[1]*rd0); pk0.y = pk2(s0[2]*rd0, s0[3]*rd0);
      pk0.z = pk2(s0[4]*rd0, s0[5]*rd0); pk0.w = pk2(s0[6]*rd0, s0[7]*rd0);
      pk1.x = pk2(s1[0]*rd1, s1[1]*rd1); pk1.y = pk2(s1[2]*rd1, s1[3]*rd1);
      pk1.z = pk2(s1[4]*rd1, s1[5]*rd1); pk1.w = pk2(s1[6]*rd1, s1[7]*rd1);
      *(uint4*)(lds_a + nl0 * DIM + (l ^ (nl0 & 15)) * 8) = pk0;
      *(uint4*)(lds_a + nl1 * DIM + (l ^ (nl1 & 15)) * 8) = pk1;
    }
  }
  __syncthreads();

  // ---- phase 2: dense MFMA ----
  const int l15 = lane & 15, l4 = lane >> 4;
  f32x4 acc[4][2];
#pragma unroll
  for (int ntl = 0; ntl < 2; ++ntl) {
    float b = bl[(wave * 2 + ntl) * 16 + l15];
#pragma unroll
    for (int rt = 0; rt < 4; ++rt) {
      f32x4 ib = {b, b, b, b};
      acc[rt][ntl] = ib;
    }
  }

#pragma unroll
  for (int kt = 0; kt < 4; ++kt) {
    const int k0 = kt * 32 + l4 * 8;
    bf16x8 b0[2], b1[2];
#pragma unroll
    for (int ntl = 0; ntl < 2; ++ntl) {
      int ncol = (wave * 2 + ntl) * 16 + l15;
      b0[ntl] = *(const bf16x8*)(Wt + (size_t)ncol * 128 + k0);          // Wl^T
      b1[ntl] = *(const bf16x8*)(Wt + (size_t)(128 + ncol) * 128 + k0);  // Wr^T
    }
#pragma unroll
    for (int rt = 0; rt < 4; ++rt) {
      const int r = rt * 16 + l15;
      const int chunk = (kt * 4 + l4) ^ l15;
      bf16x8 a8 = *(const bf16x8*)(lds_a + r * DIM + chunk * 8);
      int row = base + r;
      if (row >= NN) row = NN - 1;  // clamp: padded rows computed, never stored
      bf16x8 hh8 = *(const bf16x8*)(h + (size_t)row * DIM + k0);
#pragma unroll
      for (int ntl = 0; ntl < 2; ++ntl) {
        acc[rt][ntl] = __builtin_amdgcn_mfma_f32_16x16x32_bf16(a8, b0[ntl], acc[rt][ntl], 0, 0, 0);
        acc[rt][ntl] = __builtin_amdgcn_mfma_f32_16x16x32_bf16(hh8, b1[ntl], acc[rt][ntl], 0, 0, 0);
      }
    }
  }

  // ---- epilogue ----
#pragma unroll
  for (int rt = 0; rt < 4; ++rt)
#pragma unroll
    for (int ntl = 0; ntl < 2; ++ntl) {
      const int col = (wave * 2 + ntl) * 16 + l15;
#pragma unroll
      for (int r = 0; r < 4; ++r) {
        int row = base + rt * 16 + l4 * 4 + r;
        if (row < NN) {
          float v = acc[rt][ntl][r];
          if (RELU) v = fmaxf(v, 0.f);
          const size_t off = (size_t)row * DIM + col;
          if (WOUT) out[off] = v;
          if (WPLANES) ph[off] = f2bf(v);
        }
      }
    }
}

// ---------------------------------------------------------------------------
extern "C" void kernel_launch(void* const* d_in, const int* in_sizes, int n_in,
                              void* d_out, int out_size, void* d_ws, size_t ws_size,
                              hipStream_t stream) {
  const float* x   = (const float*)d_in[0];
  const void* edges = d_in[1];
  const float* W1l = (const float*)d_in[2];
  const float* b1l = (const float*)d_in[3];
  const float* W1r = (const float*)d_in[4];
  const float* W2l = (const float*)d_in[5];
  const float* b2l = (const float*)d_in[6];
  const float* W2r = (const float*)d_in[7];
  float* out = (float*)d_out;

  // ---- workspace layout (~71 MB; partition buffer aliases hh1: part is
  //      dead after partB, hh1 first written in fused1's epilogue)
  char* p = (char*)d_ws;
  unsigned short* Wt1 = (unsigned short*)p;               p += 2 * 128 * 128 * 2;
  unsigned short* Wt2 = (unsigned short*)p;               p += 2 * 128 * 128 * 2;
  int* cnt  = (int*)p;                                    p += (size_t)NN * 4;
  int* bcnt = (int*)p;                                    p += (size_t)NB * 4;
  int* novf = (int*)p;                                    p += 4;
  p = (char*)(((uintptr_t)p + 15) & ~(uintptr_t)15);
  int* ovf = (int*)p;                                     p += (size_t)OVF_CAP * 2 * 4;
  p = (char*)(((uintptr_t)p + 255) & ~(uintptr_t)255);
  int* ell = (int*)p;                                     p += (size_t)NB * 256 * CAP * 4;
  p = (char*)(((uintptr_t)p + 255) & ~(uintptr_t)255);
  unsigned short* hx  = (unsigned short*)p;               p += (size_t)NN * DIM * 2;
  unsigned short* hh1 = (unsigned short*)p;               p += (size_t)NN * DIM * 2;
  unsigned* part = (unsigned*)hh1;  // alias (disjoint lifetimes)

  // zero bcnt + novf in one memset (cnt fully rewritten by partB)
  hipMemsetAsync(bcnt, 0, ((size_t)NB + 1) * 4, stream);

  // partition + weight/x prep in one grid (prep fills idle CUs)
  partA_prep_kernel<<<NB + NPREP_W + NPREP_X, ATHREADS, 0, stream>>>(
      edges, bcnt, part, novf, ovf, x, W1l, W1r, W2l, W2r, Wt1, Wt2, hx);
  partB_kernel<<<NB, 256, 0, stream>>>(bcnt, part, cnt, ell, novf, ovf);

  const int fused_blocks = (NN + 63) / 64;

  // ---- layer 1: h1 = relu(mean_agg(x) @ W1l + b1l + x @ W1r) -> bf16 plane
  fused_kernel<true, true, false><<<fused_blocks, 256, 0, stream>>>(
      cnt, ell, hx, Wt1, b1l, out, hh1, novf, ovf);

  // ---- layer 2: out = mean_agg(h1) @ W2l + b2l + h1 @ W2r -> f32
  fused_kernel<false, false, true><<<fused_blocks, 256, 0, stream>>>(
      cnt, ell, hh1, Wt2, b2l, out, nullptr, novf, ovf);
}

// Round 12
// 267.280 us; speedup vs baseline: 2.0731x; 1.0044x over previous
//
#include <hip/hip_runtime.h>
#include <cstdint>
#include <cstddef>

#define NN 100000
#define EE 1600000
#define DIM 128
#define CAP 48        // ELL row capacity (mean deg 16; P(deg>48) ~ 5e-11 per node)
#define OVF_CAP 512   // overflow edge capacity (expected 0 used)

#define NB 391        // dst buckets of 256 nodes: ceil(100000/256)
#define BCAP 4608     // per-bucket partition capacity (mean 4092, +8 sigma)
#define SLOTS 32      // LDS staging slots per bucket
#define FLUSH_AT 16   // flush threshold (entries)
#define ACHUNK 4096   // edges per phase-A block -> 391 partition blocks
#define ATHREADS 512

#define NPREP_W 128                          // weight-prep blocks (65536/512)
#define NPREP_X ((NN * DIM / 4) / ATHREADS)  // x-cast blocks (6250)

typedef __attribute__((ext_vector_type(8))) short bf16x8;
typedef __attribute__((ext_vector_type(4))) float f32x4;

__device__ __forceinline__ unsigned short f2bf(float f) {
  union { float f; uint32_t u; } v; v.f = f;
  uint32_t r = v.u + 0x7FFF + ((v.u >> 16) & 1);  // RNE to bf16
  return (unsigned short)(r >> 16);
}
__device__ __forceinline__ float uaf(uint32_t u) {
  union { uint32_t u; float f; } v; v.u = u;
  return v.f;
}
__device__ __forceinline__ uint32_t pk2(float a, float b) {
  return (uint32_t)f2bf(a) | ((uint32_t)f2bf(b) << 16);
}
// pairwise bf16->f32 extraction: lo = w<<16, hi = w&0xFFFF0000 (exact)
__device__ __forceinline__ void acc_dw4(float* s, uint4 w) {
  s[0] += uaf(w.x << 16); s[1] += uaf(w.x & 0xFFFF0000u);
  s[2] += uaf(w.y << 16); s[3] += uaf(w.y & 0xFFFF0000u);
  s[4] += uaf(w.z << 16); s[5] += uaf(w.z & 0xFFFF0000u);
  s[6] += uaf(w.w << 16); s[7] += uaf(w.w & 0xFFFF0000u);
}

// ---------------------------------------------------------------------------
// partA_prep: blocks < NB partition edges into dst-buckets (LDS staging,
// per-thread flush); blocks >= NB do independent prep work (weight transpose+
// cast, x->bf16 cast) -- fills CUs that partA leaves idle (partA is LDS-bound
// at ~3 blocks/CU and only 391 blocks).
// pack = s | ((d & 255) << 17)   (s < 2^17)
// ---------------------------------------------------------------------------
__global__ __launch_bounds__(ATHREADS) void partA_prep_kernel(
    const void* __restrict__ edges, int* __restrict__ bcnt,
    unsigned* __restrict__ part, int* __restrict__ novf, int* __restrict__ ovf,
    const float* __restrict__ x,
    const float* __restrict__ W1l, const float* __restrict__ W1r,
    const float* __restrict__ W2l, const float* __restrict__ W2r,
    unsigned short* __restrict__ Wt1, unsigned short* __restrict__ Wt2,
    unsigned short* __restrict__ xhi) {
  __shared__ unsigned stage[NB][SLOTS + 1];  // +1 pad: de-alias flush banks
  __shared__ int scnt[NB];
  __shared__ int sh_i64;
  const int t = threadIdx.x;

  if (blockIdx.x >= NB) {  // ---- prep path (no LDS use) ----
    int bid = blockIdx.x - NB;
    if (bid < NPREP_W) {
      int idx = bid * ATHREADS + t;  // 65536 total
      int layer = idx >> 15;
      int rest = idx & 32767;
      int mat = rest >> 14;
      int r = rest & 16383;
      int k = r >> 7, n = r & 127;
      const float* W = layer ? (mat ? W2r : W2l) : (mat ? W1r : W1l);
      unsigned short* Wt = layer ? Wt2 : Wt1;
      Wt[((size_t)(mat * 128 + n)) * 128 + k] = f2bf(W[k * 128 + n]);
    } else {
      int i = (bid - NPREP_W) * ATHREADS + t;  // one float4 per thread
      if (i < NN * DIM / 4) {
        f32x4 v = ((const f32x4*)x)[i];
        ushort4 hi;
        hi.x = f2bf(v[0]); hi.y = f2bf(v[1]); hi.z = f2bf(v[2]); hi.w = f2bf(v[3]);
        ((ushort4*)xhi)[i] = hi;
      }
    }
    return;
  }

  // ---- partition path ----
  for (int b = t; b < NB; b += ATHREADS) scnt[b] = 0;
  if (t < 64) {
    // int64 little-endian => odd 32-bit words of first 64 entries all zero;
    // int32 => those words are random src values, all-zero impossible.
    int v = ((const int*)edges)[2 * t + 1];
    unsigned long long m = __ballot(v != 0);
    if (t == 0) sh_i64 = (m == 0ull) ? 1 : 0;
  }
  __syncthreads();
  const int i64 = sh_i64;
  const long long ebase = (long long)blockIdx.x * ACHUNK;
  const int nrounds = ACHUNK / ATHREADS;
  for (int r = 0; r < nrounds; ++r) {
    long long e = ebase + (long long)r * ATHREADS + t;
    if (e < EE) {
      int s, d;
      if (i64) {
        s = (int)((const long long*)edges)[e];
        d = (int)((const long long*)edges)[(long long)EE + e];
      } else {
        s = ((const int*)edges)[e];
        d = ((const int*)edges)[(long long)EE + e];
      }
      if ((unsigned)s < NN && (unsigned)d < NN) {
        int b = d >> 8;
        unsigned pk = (unsigned)s | ((unsigned)(d & 255) << 17);
        int pos = atomicAdd(&scnt[b], 1);
        if (pos < SLOTS) {
          stage[b][pos] = pk;
        } else {  // stage overflow (rare): direct append
          int g = atomicAdd(&bcnt[b], 1);
          if (g < BCAP) part[(size_t)b * BCAP + g] = pk;
          else { int oi = atomicAdd(novf, 1); if (oi < OVF_CAP) { ovf[oi*2] = s; ovf[oi*2+1] = d; } }
        }
      }
    }
    __syncthreads();
    const bool last = (r == nrounds - 1);
    for (int b = t; b < NB; b += ATHREADS) {  // per-thread flush (parallel chains)
      int c = scnt[b];
      if (c > SLOTS) c = SLOTS;
      if (c > 0 && (last || c >= FLUSH_AT)) {
        int g = atomicAdd(&bcnt[b], c);
        for (int i = 0; i < c; ++i) {
          int gp = g + i;
          unsigned pk = stage[b][i];
          if (gp < BCAP) {
            part[(size_t)b * BCAP + gp] = pk;
          } else {
            int oi = atomicAdd(novf, 1);
            if (oi < OVF_CAP) { ovf[oi*2] = (int)(pk & 0x1FFFF); ovf[oi*2+1] = (b << 8) | (int)(pk >> 17); }
          }
        }
        scnt[b] = 0;
      }
    }
    __syncthreads();
  }
}

// ---------------------------------------------------------------------------
// Phase B: per bucket (256 nodes), build ELL rows in LDS (LDS atomics),
// write densely coalesced. Also emits cnt (degree) -- no cnt memset needed.
// ---------------------------------------------------------------------------
__global__ __launch_bounds__(256) void partB_kernel(
    const int* __restrict__ bcnt, const unsigned* __restrict__ part,
    int* __restrict__ cnt, int* __restrict__ ell,
    int* __restrict__ novf, int* __restrict__ ovf) {
  __shared__ int lcnt[256];
  __shared__ int lell[256 * CAP];  // 48 KB
  const int t = threadIdx.x;
  const int b = blockIdx.x;
  lcnt[t] = 0;
  __syncthreads();
  int n = bcnt[b];
  if (n > BCAP) n = BCAP;
  for (int i = t; i < n; i += 256) {
    unsigned pk = part[(size_t)b * BCAP + i];
    int s = (int)(pk & 0x1FFFF);
    int dl = (int)(pk >> 17);
    int pos = atomicAdd(&lcnt[dl], 1);
    if (pos < CAP) lell[dl * CAP + pos] = s;
    else { int oi = atomicAdd(novf, 1); if (oi < OVF_CAP) { ovf[oi*2] = s; ovf[oi*2+1] = (b << 8) | dl; } }
  }
  __syncthreads();
  int4* dst = (int4*)(ell + (size_t)b * 256 * CAP);
  const int4* src = (const int4*)lell;
#pragma unroll
  for (int i = 0; i < 256 * CAP / 4 / 256; ++i) dst[t + i * 256] = src[t + i * 256];
  int node = b * 256 + t;
  if (node < NN) cnt[node] = lcnt[t];
}

// ---------------------------------------------------------------------------
// Fused gather+dense: per block of 64 nodes --
//   phase 1: gather mean-agg of the block's nodes from ELL (random bf16 row
//            reads, quarter-wave per row, 2 nodes x 4-deep in flight) into a
//            swizzled LDS tile (64 x 128 bf16, chunk = c16 ^ (row&15) -> <=2-way
//            bank aliasing on both the write and the ds_read_b128).
//   phase 2: dense MFMA out = act(aggLDS @ Wl + bl + h @ Wr); weights loaded
//            per-kt (L2-hot) to keep VGPR low for phase-1 occupancy.
// Deletes the 51 MB/layer agg round-trip through global.
// ---------------------------------------------------------------------------
template <bool RELU, bool WPLANES, bool WOUT>
__global__ __launch_bounds__(256, 3) void fused_kernel(
    const int* __restrict__ cnt, const int* __restrict__ ell,
    const unsigned short* __restrict__ h, const unsigned short* __restrict__ Wt,
    const float* __restrict__ bl, float* __restrict__ out,
    unsigned short* __restrict__ ph,
    const int* __restrict__ novf, const int* __restrict__ ovf) {
  __shared__ unsigned short lds_a[64 * DIM];  // 16 KB, swizzled 16B chunks
  const int t = threadIdx.x;
  const int wave = t >> 6, lane = t & 63;
  const int q = lane >> 4;   // quarter 0..3
  const int l = lane & 15;   // lane-in-quarter: cols l*8..l*8+7
  const int base = blockIdx.x * 64;

  // ---- phase 1: each wave gathers 16 nodes, 2 concurrently ----
  for (int i = 0; i < 16; i += 2) {
    const int nl0 = wave * 16 + i;
    const int nl1 = nl0 + 1;
    const int node0 = base + nl0, node1 = base + nl1;
    const int dc0 = (node0 < NN) ? cnt[node0] : 0;
    const int dc1 = (node1 < NN) ? cnt[node1] : 0;
    const int n0 = dc0 < CAP ? dc0 : CAP;
    const int n1 = dc1 < CAP ? dc1 : CAP;
    const int* r0 = ell + (size_t)node0 * CAP;
    const int* r1 = ell + (size_t)node1 * CAP;
    float s0[8] = {0.f,0.f,0.f,0.f,0.f,0.f,0.f,0.f};
    float s1[8] = {0.f,0.f,0.f,0.f,0.f,0.f,0.f,0.f};
    const int nmax = n0 > n1 ? n0 : n1;
    for (int p = q; p < nmax; p += 16) {  // 8 independent row loads in flight
      uint4 w[8];
#pragma unroll
      for (int j = 0; j < 4; ++j)
        if (p + j * 4 < n0) w[j] = *(const uint4*)(h + (size_t)r0[p + j * 4] * DIM + l * 8);
#pragma unroll
      for (int j = 0; j < 4; ++j)
        if (p + j * 4 < n1) w[4 + j] = *(const uint4*)(h + (size_t)r1[p + j * 4] * DIM + l * 8);
#pragma unroll
      for (int j = 0; j < 4; ++j)
        if (p + j * 4 < n0) acc_dw4(s0, w[j]);
#pragma unroll
      for (int j = 0; j < 4; ++j)
        if (p + j * 4 < n1) acc_dw4(s1, w[4 + j]);
    }
#pragma unroll
    for (int k = 0; k < 8; ++k) {
      s0[k] += __shfl_xor(s0[k], 16, 64);
      s0[k] += __shfl_xor(s0[k], 32, 64);
      s1[k] += __shfl_xor(s1[k], 16, 64);
      s1[k] += __shfl_xor(s1[k], 32, 64);
    }
    if (q == 0) {
      // overflow fixup (expected-empty list scan)
      if (dc0 > CAP || dc1 > CAP) {
        int no = *novf;
        if (no > OVF_CAP) no = OVF_CAP;
        for (int k = 0; k < no; ++k) {
          int od = ovf[k * 2 + 1];
          if (od == node0 && dc0 > CAP) {
            uint4 w = *(const uint4*)(h + (size_t)ovf[k * 2] * DIM + l * 8);
            acc_dw4(s0, w);
          }
          if (od == node1 && dc1 > CAP) {
            uint4 w = *(const uint4*)(h + (size_t)ovf[k * 2] * DIM + l * 8);
            acc_dw4(s1, w);
          }
        }
      }
      const float rd0 = 1.0f / fmaxf((float)dc0, 1.0f);
      const float rd1 = 1.0f / fmaxf((float)dc1, 1.0f);
      uint4 pk0, pk1;
      pk0.x = pk2(s0[0]*rd0, s0[1]*rd0); pk0.y = pk2(s0[2]*rd0, s0[3]*rd0);
      pk0.z = pk2(s0[4]*rd0, s0[5]*rd0); pk0.w = pk2(s0[6]*rd0, s0[7]*rd0);
      pk1.x = pk2(s1[0]*rd1, s1[1]*rd1); pk1.y = pk2(s1[2]*rd1, s1[3]*rd1);
      pk1.z = pk2(s1[4]*rd1, s1[5]*rd1); pk1.w = pk2(s1[6]*rd1, s1[7]*rd1);
      *(uint4*)(lds_a + nl0 * DIM + (l ^ (nl0 & 15)) * 8) = pk0;
      *(uint4*)(lds_a + nl1 * DIM + (l ^ (nl1 & 15)) * 8) = pk1;
    }
  }
  __syncthreads();

  // ---- phase 2: dense MFMA ----
  const int l15 = lane & 15, l4 = lane >> 4;
  f32x4 acc[4][2];
#pragma unroll
  for (int ntl = 0; ntl < 2; ++ntl) {
    float b = bl[(wave * 2 + ntl) * 16 + l15];
#pragma unroll
    for (int rt = 0; rt < 4; ++rt) {
      f32x4 ib = {b, b, b, b};
      acc[rt][ntl] = ib;
    }
  }

#pragma unroll
  for (int kt = 0; kt < 4; ++kt) {
    const int k0 = kt * 32 + l4 * 8;
    bf16x8 b0[2], b1[2];
#pragma unroll
    for (int ntl = 0; ntl < 2; ++ntl) {
      int ncol = (wave * 2 + ntl) * 16 + l15;
      b0[ntl] = *(const bf16x8*)(Wt + (size_t)ncol * 128 + k0);          // Wl^T
      b1[ntl] = *(const bf16x8*)(Wt + (size_t)(128 + ncol) * 128 + k0);  // Wr^T
    }
#pragma unroll
    for (int rt = 0; rt < 4; ++rt) {
      const int r = rt * 16 + l15;
      const int chunk = (kt * 4 + l4) ^ l15;
      bf16x8 a8 = *(const bf16x8*)(lds_a + r * DIM + chunk * 8);
      int row = base + r;
      if (row >= NN) row = NN - 1;  // clamp: padded rows computed, never stored
      bf16x8 hh8 = *(const bf16x8*)(h + (size_t)row * DIM + k0);
#pragma unroll
      for (int ntl = 0; ntl < 2; ++ntl) {
        acc[rt][ntl] = __builtin_amdgcn_mfma_f32_16x16x32_bf16(a8, b0[ntl], acc[rt][ntl], 0, 0, 0);
        acc[rt][ntl] = __builtin_amdgcn_mfma_f32_16x16x32_bf16(hh8, b1[ntl], acc[rt][ntl], 0, 0, 0);
      }
    }
  }

  // ---- epilogue ----
#pragma unroll
  for (int rt = 0; rt < 4; ++rt)
#pragma unroll
    for (int ntl = 0; ntl < 2; ++ntl) {
      const int col = (wave * 2 + ntl) * 16 + l15;
#pragma unroll
      for (int r = 0; r < 4; ++r) {
        int row = base + rt * 16 + l4 * 4 + r;
        if (row < NN) {
          float v = acc[rt][ntl][r];
          if (RELU) v = fmaxf(v, 0.f);
          const size_t off = (size_t)row * DIM + col;
          if (WOUT) out[off] = v;
          if (WPLANES) ph[off] = f2bf(v);
        }
      }
    }
}

// ---------------------------------------------------------------------------
extern "C" void kernel_launch(void* const* d_in, const int* in_sizes, int n_in,
                              void* d_out, int out_size, void* d_ws, size_t ws_size,
                              hipStream_t stream) {
  const float* x   = (const float*)d_in[0];
  const void* edges = d_in[1];
  const float* W1l = (const float*)d_in[2];
  const float* b1l = (const float*)d_in[3];
  const float* W1r = (const float*)d_in[4];
  const float* W2l = (const float*)d_in[5];
  const float* b2l = (const float*)d_in[6];
  const float* W2r = (const float*)d_in[7];
  float* out = (float*)d_out;

  // ---- workspace layout (~71 MB; partition buffer aliases hh1: part is
  //      dead after partB, hh1 first written in fused1's epilogue)
  char* p = (char*)d_ws;
  unsigned short* Wt1 = (unsigned short*)p;               p += 2 * 128 * 128 * 2;
  unsigned short* Wt2 = (unsigned short*)p;               p += 2 * 128 * 128 * 2;
  int* cnt  = (int*)p;                                    p += (size_t)NN * 4;
  int* bcnt = (int*)p;                                    p += (size_t)NB * 4;
  int* novf = (int*)p;                                    p += 4;
  p = (char*)(((uintptr_t)p + 15) & ~(uintptr_t)15);
  int* ovf = (int*)p;                                     p += (size_t)OVF_CAP * 2 * 4;
  p = (char*)(((uintptr_t)p + 255) & ~(uintptr_t)255);
  int* ell = (int*)p;                                     p += (size_t)NB * 256 * CAP * 4;
  p = (char*)(((uintptr_t)p + 255) & ~(uintptr_t)255);
  unsigned short* hx  = (unsigned short*)p;               p += (size_t)NN * DIM * 2;
  unsigned short* hh1 = (unsigned short*)p;               p += (size_t)NN * DIM * 2;
  unsigned* part = (unsigned*)hh1;  // alias (disjoint lifetimes)

  // zero bcnt + novf in one memset (cnt fully rewritten by partB)
  hipMemsetAsync(bcnt, 0, ((size_t)NB + 1) * 4, stream);

  // partition + weight/x prep in one grid (prep fills idle CUs)
  partA_prep_kernel<<<NB + NPREP_W + NPREP_X, ATHREADS, 0, stream>>>(
      edges, bcnt, part, novf, ovf, x, W1l, W1r, W2l, W2r, Wt1, Wt2, hx);
  partB_kernel<<<NB, 256, 0, stream>>>(bcnt, part, cnt, ell, novf, ovf);

  const int fused_blocks = (NN + 63) / 64;

  // ---- layer 1: h1 = relu(mean_agg(x) @ W1l + b1l + x @ W1r) -> bf16 plane
  fused_kernel<true, true, false><<<fused_blocks, 256, 0, stream>>>(
      cnt, ell, hx, Wt1, b1l, out, hh1, novf, ovf);

  // ---- layer 2: out = mean_agg(h1) @ W2l + b2l + h1 @ W2r -> f32
  fused_kernel<false, false, true><<<fused_blocks, 256, 0, stream>>>(
      cnt, ell, hh1, Wt2, b2l, out, nullptr, novf, ovf);
}

// Round 14
// 252.739 us; speedup vs baseline: 2.1923x; 1.0575x over previous
//
#include <hip/hip_runtime.h>
#include <cstdint>
#include <cstddef>

#define NN 100000
#define EE 1600000
#define DIM 128
#define CAP 48        // ELL row capacity (mean deg 16; P(deg>48) ~ 5e-11 per node)
#define OVF_CAP 512   // overflow edge capacity (expected 0 used)

#define NB 391        // dst buckets of 256 nodes: ceil(100000/256)
#define BCAP 4608     // per-bucket partition capacity (mean 4092, +8 sigma)
#define SLOTS 32      // LDS staging slots per bucket
#define FLUSH_AT 16   // flush threshold (entries)
#define ACHUNK 4096   // edges per phase-A partition block
#define ATHREADS 512

#define NPREP_W 128                          // weight-prep blocks (65536/512)
#define NPREP_X ((NN * DIM / 4) / ATHREADS)  // x-fp8-cast blocks (6250)

#if __has_builtin(__builtin_amdgcn_cvt_pk_f32_fp8) && __has_builtin(__builtin_amdgcn_cvt_pk_fp8_f32)
#define HAVE_FP8 1
#else
#define HAVE_FP8 0
#endif

typedef __attribute__((ext_vector_type(8))) short bf16x8;
typedef __attribute__((ext_vector_type(4))) float f32x4;
typedef __attribute__((ext_vector_type(2))) float f32x2;

__device__ __forceinline__ unsigned short f2bf(float f) {
  union { float f; uint32_t u; } v; v.f = f;
  uint32_t r = v.u + 0x7FFF + ((v.u >> 16) & 1);  // RNE to bf16
  return (unsigned short)(r >> 16);
}
__device__ __forceinline__ uint32_t pk2(float a, float b) {
  return (uint32_t)f2bf(a) | ((uint32_t)f2bf(b) << 16);
}

// ---- fp8 e4m3fn helpers (HW path + software fallback) ----------------------
// NOTE: the builtin's word-select arg must be a LITERAL constant -> template.
template <bool HI>
__device__ __forceinline__ uint32_t f2fp8_pair(float a, float b, uint32_t old) {
#if HAVE_FP8
  return (uint32_t)__builtin_amdgcn_cvt_pk_fp8_f32(a, b, (int)old, HI);
#else
  auto enc = [](float f) -> uint32_t {
    union { float f; uint32_t u; } v; v.f = f;
    uint32_t s = (v.u >> 31) << 7;
    uint32_t m = v.u & 0x7FFFFFFF;
    if (m < 0x3C000000u) {  // < 2^-7: subnormal territory
      union { uint32_t u; float f; } w; w.u = m;
      int q = (int)(w.f * 512.0f + 0.5f);
      if (q > 7) return s | (1u << 3);
      return s | (uint32_t)q;
    }
    uint32_t u2 = m + 0x00080000u;  // round into mantissa bit 20
    int e = (int)(u2 >> 23) - 127;
    if (e > 8) return s | 0x7E;  // clamp to 448
    return s | ((uint32_t)(e + 7) << 3) | ((u2 >> 20) & 7);
  };
  uint32_t pr = enc(a) | (enc(b) << 8);
  return HI ? ((old & 0x0000FFFFu) | (pr << 16)) : ((old & 0xFFFF0000u) | pr);
#endif
}

__device__ __forceinline__ void acc_fp8x8(float* s, uint2 w) {
#if HAVE_FP8
  f32x2 f;
  f = __builtin_amdgcn_cvt_pk_f32_fp8((int)w.x, false); s[0] += f.x; s[1] += f.y;
  f = __builtin_amdgcn_cvt_pk_f32_fp8((int)w.x, true);  s[2] += f.x; s[3] += f.y;
  f = __builtin_amdgcn_cvt_pk_f32_fp8((int)w.y, false); s[4] += f.x; s[5] += f.y;
  f = __builtin_amdgcn_cvt_pk_f32_fp8((int)w.y, true);  s[6] += f.x; s[7] += f.y;
#else
  auto dec = [](uint32_t b) -> float {
    uint32_t sg = (b >> 7) & 1, e = (b >> 3) & 15, m = b & 7;
    if (e == 0) return (sg ? -1.f : 1.f) * (float)m * 0.001953125f;  // m * 2^-9
    union { uint32_t u; float f; } w;
    w.u = (sg << 31) | ((e + 120) << 23) | (m << 20);
    return w.f;
  };
#pragma unroll
  for (int i = 0; i < 4; ++i) s[i] += dec((w.x >> (i * 8)) & 0xFF);
#pragma unroll
  for (int i = 0; i < 4; ++i) s[4 + i] += dec((w.y >> (i * 8)) & 0xFF);
#endif
}

// f32x8 -> bf16x8 via HW packed convert (RNE)
__device__ __forceinline__ bf16x8 cvt8(f32x4 a, f32x4 b) {
  union { uint32_t u[4]; bf16x8 v; } r;
  asm("v_cvt_pk_bf16_f32 %0, %1, %2" : "=v"(r.u[0]) : "v"(a[0]), "v"(a[1]));
  asm("v_cvt_pk_bf16_f32 %0, %1, %2" : "=v"(r.u[1]) : "v"(a[2]), "v"(a[3]));
  asm("v_cvt_pk_bf16_f32 %0, %1, %2" : "=v"(r.u[2]) : "v"(b[0]), "v"(b[1]));
  asm("v_cvt_pk_bf16_f32 %0, %1, %2" : "=v"(r.u[3]) : "v"(b[2]), "v"(b[3]));
  return r.v;
}

// ---------------------------------------------------------------------------
// partA_prep: blocks < NB partition edges into dst-buckets (LDS staging,
// per-thread flush -- round-7 proved wave-serial flush regresses 3x);
// blocks >= NB do prep (weight transpose+bf16 cast, x -> fp8 plane).
// pack = s | ((d & 255) << 17)   (s < 2^17)
// ---------------------------------------------------------------------------
__global__ __launch_bounds__(ATHREADS) void partA_prep_kernel(
    const void* __restrict__ edges, int* __restrict__ bcnt,
    unsigned* __restrict__ part, int* __restrict__ novf, int* __restrict__ ovf,
    const float* __restrict__ x,
    const float* __restrict__ W1l, const float* __restrict__ W1r,
    const float* __restrict__ W2l, const float* __restrict__ W2r,
    unsigned short* __restrict__ Wt1, unsigned short* __restrict__ Wt2,
    unsigned char* __restrict__ x8) {
  __shared__ unsigned stage[NB][SLOTS + 1];  // +1 pad: de-alias flush banks
  __shared__ int scnt[NB];
  __shared__ int sh_i64;
  const int t = threadIdx.x;

  if (blockIdx.x >= NB) {  // ---- prep path (no LDS use) ----
    int bid = blockIdx.x - NB;
    if (bid < NPREP_W) {
      int idx = bid * ATHREADS + t;  // 65536 total
      int layer = idx >> 15;
      int rest = idx & 32767;
      int mat = rest >> 14;
      int r = rest & 16383;
      int k = r >> 7, n = r & 127;
      const float* W = layer ? (mat ? W2r : W2l) : (mat ? W1r : W1l);
      unsigned short* Wt = layer ? Wt2 : Wt1;
      Wt[((size_t)(mat * 128 + n)) * 128 + k] = f2bf(W[k * 128 + n]);
    } else {
      int i = (bid - NPREP_W) * ATHREADS + t;  // one float4 -> one fp8x4 dword
      if (i < NN * DIM / 4) {
        f32x4 v = ((const f32x4*)x)[i];
        uint32_t pk = f2fp8_pair<false>(v[0], v[1], 0);
        pk = f2fp8_pair<true>(v[2], v[3], pk);
        ((uint32_t*)x8)[i] = pk;
      }
    }
    return;
  }

  // ---- partition path ----
  for (int b = t; b < NB; b += ATHREADS) scnt[b] = 0;
  if (t < 64) {
    // int64 little-endian => odd 32-bit words of first 64 entries all zero;
    // int32 => those words are random src values, all-zero impossible.
    int v = ((const int*)edges)[2 * t + 1];
    unsigned long long m = __ballot(v != 0);
    if (t == 0) sh_i64 = (m == 0ull) ? 1 : 0;
  }
  __syncthreads();
  const int i64 = sh_i64;
  const long long ebase = (long long)blockIdx.x * ACHUNK;
  const int nrounds = ACHUNK / ATHREADS;
  for (int r = 0; r < nrounds; ++r) {
    long long e = ebase + (long long)r * ATHREADS + t;
    if (e < EE) {
      int s, d;
      if (i64) {
        s = (int)((const long long*)edges)[e];
        d = (int)((const long long*)edges)[(long long)EE + e];
      } else {
        s = ((const int*)edges)[e];
        d = ((const int*)edges)[(long long)EE + e];
      }
      if ((unsigned)s < NN && (unsigned)d < NN) {
        int b = d >> 8;
        unsigned pk = (unsigned)s | ((unsigned)(d & 255) << 17);
        int pos = atomicAdd(&scnt[b], 1);
        if (pos < SLOTS) {
          stage[b][pos] = pk;
        } else {  // stage overflow (rare): direct append
          int g = atomicAdd(&bcnt[b], 1);
          if (g < BCAP) part[(size_t)b * BCAP + g] = pk;
          else { int oi = atomicAdd(novf, 1); if (oi < OVF_CAP) { ovf[oi*2] = s; ovf[oi*2+1] = d; } }
        }
      }
    }
    __syncthreads();
    const bool last = (r == nrounds - 1);
    for (int b = t; b < NB; b += ATHREADS) {  // per-thread flush (parallel chains)
      int c = scnt[b];
      if (c > SLOTS) c = SLOTS;
      if (c > 0 && (last || c >= FLUSH_AT)) {
        int g = atomicAdd(&bcnt[b], c);
        for (int i = 0; i < c; ++i) {
          int gp = g + i;
          unsigned pk = stage[b][i];
          if (gp < BCAP) {
            part[(size_t)b * BCAP + gp] = pk;
          } else {
            int oi = atomicAdd(novf, 1);
            if (oi < OVF_CAP) { ovf[oi*2] = (int)(pk & 0x1FFFF); ovf[oi*2+1] = (b << 8) | (int)(pk >> 17); }
          }
        }
        scnt[b] = 0;
      }
    }
    __syncthreads();
  }
}

// ---------------------------------------------------------------------------
// Phase B: per bucket (256 nodes), build ELL rows in LDS (LDS atomics),
// write densely coalesced. Also emits cnt (degree).
// ---------------------------------------------------------------------------
__global__ __launch_bounds__(256) void partB_kernel(
    const int* __restrict__ bcnt, const unsigned* __restrict__ part,
    int* __restrict__ cnt, int* __restrict__ ell,
    int* __restrict__ novf, int* __restrict__ ovf) {
  __shared__ int lcnt[256];
  __shared__ int lell[256 * CAP];  // 48 KB
  const int t = threadIdx.x;
  const int b = blockIdx.x;
  lcnt[t] = 0;
  __syncthreads();
  int n = bcnt[b];
  if (n > BCAP) n = BCAP;
  for (int i = t; i < n; i += 256) {
    unsigned pk = part[(size_t)b * BCAP + i];
    int s = (int)(pk & 0x1FFFF);
    int dl = (int)(pk >> 17);
    int pos = atomicAdd(&lcnt[dl], 1);
    if (pos < CAP) lell[dl * CAP + pos] = s;
    else { int oi = atomicAdd(novf, 1); if (oi < OVF_CAP) { ovf[oi*2] = s; ovf[oi*2+1] = (b << 8) | dl; } }
  }
  __syncthreads();
  int4* dst = (int4*)(ell + (size_t)b * 256 * CAP);
  const int4* src = (const int4*)lell;
#pragma unroll
  for (int i = 0; i < 256 * CAP / 4 / 256; ++i) dst[t + i * 256] = src[t + i * 256];
  int node = b * 256 + t;
  if (node < NN) cnt[node] = lcnt[t];
}

// ---------------------------------------------------------------------------
// Gather-aggregate from ELL over fp8 rows (128 B = ONE cache line per nbr).
// One wave per node; quarter-wave per neighbor row (lane = q*16+l, lane owns
// cols l*8..l*8+7 as uint2). 4-deep unroll -> 16 rows in flight per wave.
// f32 accumulate; writes bf16 agg plane.
// ---------------------------------------------------------------------------
__global__ __launch_bounds__(256) void gather_ell_kernel(
    const int* __restrict__ cnt, const int* __restrict__ ell,
    const unsigned char* __restrict__ h8, unsigned short* __restrict__ ahi,
    const int* __restrict__ novf, const int* __restrict__ ovf) {
  const int node = blockIdx.x * 4 + (threadIdx.x >> 6);
  const int lane = threadIdx.x & 63;
  const int q = lane >> 4;       // quarter 0..3
  const int l = lane & 15;       // lane-in-quarter: cols l*8..l*8+7
  if (node >= NN) return;
  const int dcnt = cnt[node];
  const int n = dcnt < CAP ? dcnt : CAP;
  const int* row = ell + (size_t)node * CAP;
  float s[8] = {0.f, 0.f, 0.f, 0.f, 0.f, 0.f, 0.f, 0.f};
  int p = q;
  for (; p + 12 < n; p += 16) {  // 4 independent row loads in flight
    uint2 w0 = *(const uint2*)(h8 + (size_t)row[p] * DIM + l * 8);
    uint2 w1 = *(const uint2*)(h8 + (size_t)row[p + 4] * DIM + l * 8);
    uint2 w2 = *(const uint2*)(h8 + (size_t)row[p + 8] * DIM + l * 8);
    uint2 w3 = *(const uint2*)(h8 + (size_t)row[p + 12] * DIM + l * 8);
    acc_fp8x8(s, w0);
    acc_fp8x8(s, w1);
    acc_fp8x8(s, w2);
    acc_fp8x8(s, w3);
  }
  for (; p < n; p += 4) {
    uint2 w0 = *(const uint2*)(h8 + (size_t)row[p] * DIM + l * 8);
    acc_fp8x8(s, w0);
  }
#pragma unroll
  for (int i = 0; i < 8; ++i) {
    s[i] += __shfl_xor(s[i], 16, 64);
    s[i] += __shfl_xor(s[i], 32, 64);
  }
  if (q == 0) {
    if (dcnt > CAP) {  // overflow fixup: scan tiny list (expected empty)
      int no = *novf;
      if (no > OVF_CAP) no = OVF_CAP;
      for (int i = 0; i < no; ++i) {
        if (ovf[i * 2 + 1] == node) {
          uint2 w0 = *(const uint2*)(h8 + (size_t)ovf[i * 2] * DIM + l * 8);
          acc_fp8x8(s, w0);
        }
      }
    }
    const float rd = 1.0f / fmaxf((float)dcnt, 1.0f);
    uint4 o;
    o.x = pk2(s[0] * rd, s[1] * rd);
    o.y = pk2(s[2] * rd, s[3] * rd);
    o.z = pk2(s[4] * rd, s[5] * rd);
    o.w = pk2(s[6] * rd, s[7] * rd);
    *(uint4*)(ahi + (size_t)node * DIM + l * 8) = o;
  }
}

// ---------------------------------------------------------------------------
// Dense via MFMA: out = act(agg_bf16 @ Wl + bl + h_f32 @ Wr).
// h read as f32 (x or d_out-resident h1), converted in-register via
// v_cvt_pk_bf16_f32 (4 instr / 8 elems). Epilogue writes f32 out and
// (layer 1) the fp8 plane for the next gather.
// NOTE: h and out may alias (layer 2, in-place): no __restrict__ on them;
// all h reads complete before the post-barrier writes.
// ---------------------------------------------------------------------------
template <bool RELU, bool WFP8>
__global__ __launch_bounds__(256, 2) void dense_mfma_kernel(
    const unsigned short* __restrict__ ahi, const float* h,
    const unsigned short* __restrict__ Wt, const float* __restrict__ bl,
    float* out, unsigned char* __restrict__ ph8, int n) {
  const int t = threadIdx.x;
  const int wave = t >> 6, lane = t & 63;
  const int l15 = lane & 15, l4 = lane >> 4;
  const int base = blockIdx.x * 64;

  bf16x8 bfr[2][4][2];
#pragma unroll
  for (int mat = 0; mat < 2; ++mat)
#pragma unroll
    for (int kt = 0; kt < 4; ++kt)
#pragma unroll
      for (int ntl = 0; ntl < 2; ++ntl) {
        int ncol = (wave * 2 + ntl) * 16 + l15;
        int k0 = kt * 32 + l4 * 8;
        bfr[mat][kt][ntl] = *(const bf16x8*)(Wt + ((size_t)(mat * 128 + ncol)) * 128 + k0);
      }

  f32x4 acc[4][2];
#pragma unroll
  for (int ntl = 0; ntl < 2; ++ntl) {
    float b = bl[(wave * 2 + ntl) * 16 + l15];
#pragma unroll
    for (int rt = 0; rt < 4; ++rt) {
      f32x4 ib = {b, b, b, b};
      acc[rt][ntl] = ib;
    }
  }

#pragma unroll
  for (int kt = 0; kt < 4; ++kt) {
    const int k0 = kt * 32 + l4 * 8;
#pragma unroll
    for (int rt = 0; rt < 4; ++rt) {
      int row = base + rt * 16 + l15;
      if (row >= n) row = n - 1;  // clamp: padded rows computed but never stored
      const size_t off = (size_t)row * DIM + k0;
      bf16x8 a8 = *(const bf16x8*)(ahi + off);
      f32x4 h0 = *(const f32x4*)(h + off);
      f32x4 h1 = *(const f32x4*)(h + off + 4);
      bf16x8 hh8 = cvt8(h0, h1);
#pragma unroll
      for (int ntl = 0; ntl < 2; ++ntl) {
        acc[rt][ntl] = __builtin_amdgcn_mfma_f32_16x16x32_bf16(a8, bfr[0][kt][ntl], acc[rt][ntl], 0, 0, 0);
        acc[rt][ntl] = __builtin_amdgcn_mfma_f32_16x16x32_bf16(hh8, bfr[1][kt][ntl], acc[rt][ntl], 0, 0, 0);
      }
    }
  }

  __syncthreads();  // all h reads complete before in-place writes

#pragma unroll
  for (int rt = 0; rt < 4; ++rt)
#pragma unroll
    for (int ntl = 0; ntl < 2; ++ntl) {
      const int col = (wave * 2 + ntl) * 16 + l15;
#pragma unroll
      for (int r = 0; r < 4; ++r) {
        int row = base + rt * 16 + l4 * 4 + r;
        if (row < n) {
          float v = acc[rt][ntl][r];
          if (RELU) v = fmaxf(v, 0.f);
          const size_t off = (size_t)row * DIM + col;
          out[off] = v;
          if (WFP8) ph8[off] = (unsigned char)(f2fp8_pair<false>(v, v, 0) & 0xFF);
        }
      }
    }
}

// ---------------------------------------------------------------------------
extern "C" void kernel_launch(void* const* d_in, const int* in_sizes, int n_in,
                              void* d_out, int out_size, void* d_ws, size_t ws_size,
                              hipStream_t stream) {
  const float* x   = (const float*)d_in[0];
  const void* edges = d_in[1];
  const float* W1l = (const float*)d_in[2];
  const float* b1l = (const float*)d_in[3];
  const float* W1r = (const float*)d_in[4];
  const float* W2l = (const float*)d_in[5];
  const float* b2l = (const float*)d_in[6];
  const float* W2r = (const float*)d_in[7];
  float* out = (float*)d_out;

  // ---- workspace layout (~71 MB; part aliases h8: part dead after partB,
  //      h8 first written by dense1's epilogue)
  char* p = (char*)d_ws;
  unsigned short* Wt1 = (unsigned short*)p;               p += 2 * 128 * 128 * 2;
  unsigned short* Wt2 = (unsigned short*)p;               p += 2 * 128 * 128 * 2;
  int* cnt  = (int*)p;                                    p += (size_t)NN * 4;
  int* bcnt = (int*)p;                                    p += (size_t)NB * 4;
  int* novf = (int*)p;                                    p += 4;
  p = (char*)(((uintptr_t)p + 15) & ~(uintptr_t)15);
  int* ovf = (int*)p;                                     p += (size_t)OVF_CAP * 2 * 4;
  p = (char*)(((uintptr_t)p + 255) & ~(uintptr_t)255);
  int* ell = (int*)p;                                     p += (size_t)NB * 256 * CAP * 4;
  p = (char*)(((uintptr_t)p + 255) & ~(uintptr_t)255);
  unsigned short* ahi = (unsigned short*)p;               p += (size_t)NN * DIM * 2;
  unsigned char* x8 = (unsigned char*)p;                  p += (size_t)NN * DIM;
  unsigned char* h8 = (unsigned char*)p;                  p += (size_t)NN * DIM;
  unsigned* part = (unsigned*)h8;  // alias (disjoint lifetimes)

  // zero bcnt + novf in one memset (cnt fully rewritten by partB)
  (void)hipMemsetAsync(bcnt, 0, ((size_t)NB + 1) * 4, stream);

  // partition + weight/x prep in one grid (prep fills idle CUs)
  partA_prep_kernel<<<NB + NPREP_W + NPREP_X, ATHREADS, 0, stream>>>(
      edges, bcnt, part, novf, ovf, x, W1l, W1r, W2l, W2r, Wt1, Wt2, x8);
  partB_kernel<<<NB, 256, 0, stream>>>(bcnt, part, cnt, ell, novf, ovf);

  const int gather_blocks = (NN + 3) / 4;
  const int dense_blocks = (NN + 63) / 64;

  // ---- layer 1: h1 = relu(mean_agg(x) @ W1l + b1l + x @ W1r)
  //      -> d_out (f32) + h8 (fp8 plane for gather2)
  gather_ell_kernel<<<gather_blocks, 256, 0, stream>>>(cnt, ell, x8, ahi, novf, ovf);
  dense_mfma_kernel<true, true><<<dense_blocks, 256, 0, stream>>>(
      ahi, x, Wt1, b1l, out, h8, NN);

  // ---- layer 2: out = mean_agg(h1) @ W2l + b2l + h1 @ W2r  (in-place f32)
  gather_ell_kernel<<<gather_blocks, 256, 0, stream>>>(cnt, ell, h8, ahi, novf, ovf);
  dense_mfma_kernel<false, false><<<dense_blocks, 256, 0, stream>>>(
      ahi, out, Wt2, b2l, out, nullptr, NN);
}

// Round 15
// 230.909 us; speedup vs baseline: 2.3996x; 1.0945x over previous
//
#include <hip/hip_runtime.h>
#include <cstdint>
#include <cstddef>

#define NN 100000
#define EE 1600000
#define DIM 128
#define CAP 48        // ELL row capacity (mean deg 16; P(deg>48) ~ 5e-11 per node)
#define OVF_CAP 512   // overflow edge capacity (expected 0 used)

#define NB 391        // dst buckets of 256 nodes: ceil(100000/256)
#define BCAP 4608     // per-bucket partition capacity (mean 4092, +8 sigma)
#define SLOTS 32      // LDS staging slots per bucket
#define FLUSH_AT 16   // flush threshold (entries)
#define ACHUNK 4096   // edges per phase-A partition block
#define ATHREADS 512

#define NPREP_W 128                          // weight-prep blocks (65536/512)
#define NPREP_X ((NN * DIM / 4) / ATHREADS)  // x-cast blocks (6250)

#if __has_builtin(__builtin_amdgcn_cvt_pk_f32_fp8) && __has_builtin(__builtin_amdgcn_cvt_pk_fp8_f32)
#define HAVE_FP8 1
#else
#define HAVE_FP8 0
#endif

typedef __attribute__((ext_vector_type(8))) short bf16x8;
typedef __attribute__((ext_vector_type(4))) float f32x4;
typedef __attribute__((ext_vector_type(2))) float f32x2;

__device__ __forceinline__ unsigned short f2bf(float f) {
  union { float f; uint32_t u; } v; v.f = f;
  uint32_t r = v.u + 0x7FFF + ((v.u >> 16) & 1);  // RNE to bf16
  return (unsigned short)(r >> 16);
}
__device__ __forceinline__ uint32_t pk2(float a, float b) {
  return (uint32_t)f2bf(a) | ((uint32_t)f2bf(b) << 16);
}

// ---- fp8 e4m3fn helpers (HW path + software fallback) ----------------------
// NOTE: the builtin's word-select arg must be a LITERAL constant -> template.
template <bool HI>
__device__ __forceinline__ uint32_t f2fp8_pair(float a, float b, uint32_t old) {
#if HAVE_FP8
  return (uint32_t)__builtin_amdgcn_cvt_pk_fp8_f32(a, b, (int)old, HI);
#else
  auto enc = [](float f) -> uint32_t {
    union { float f; uint32_t u; } v; v.f = f;
    uint32_t s = (v.u >> 31) << 7;
    uint32_t m = v.u & 0x7FFFFFFF;
    if (m < 0x3C000000u) {  // < 2^-7: subnormal territory
      union { uint32_t u; float f; } w; w.u = m;
      int q = (int)(w.f * 512.0f + 0.5f);
      if (q > 7) return s | (1u << 3);
      return s | (uint32_t)q;
    }
    uint32_t u2 = m + 0x00080000u;  // round into mantissa bit 20
    int e = (int)(u2 >> 23) - 127;
    if (e > 8) return s | 0x7E;  // clamp to 448
    return s | ((uint32_t)(e + 7) << 3) | ((u2 >> 20) & 7);
  };
  uint32_t pr = enc(a) | (enc(b) << 8);
  return HI ? ((old & 0x0000FFFFu) | (pr << 16)) : ((old & 0xFFFF0000u) | pr);
#endif
}

__device__ __forceinline__ void acc_fp8x8(float* s, uint2 w) {
#if HAVE_FP8
  f32x2 f;
  f = __builtin_amdgcn_cvt_pk_f32_fp8((int)w.x, false); s[0] += f.x; s[1] += f.y;
  f = __builtin_amdgcn_cvt_pk_f32_fp8((int)w.x, true);  s[2] += f.x; s[3] += f.y;
  f = __builtin_amdgcn_cvt_pk_f32_fp8((int)w.y, false); s[4] += f.x; s[5] += f.y;
  f = __builtin_amdgcn_cvt_pk_f32_fp8((int)w.y, true);  s[6] += f.x; s[7] += f.y;
#else
  auto dec = [](uint32_t b) -> float {
    uint32_t sg = (b >> 7) & 1, e = (b >> 3) & 15, m = b & 7;
    if (e == 0) return (sg ? -1.f : 1.f) * (float)m * 0.001953125f;  // m * 2^-9
    union { uint32_t u; float f; } w;
    w.u = (sg << 31) | ((e + 120) << 23) | (m << 20);
    return w.f;
  };
#pragma unroll
  for (int i = 0; i < 4; ++i) s[i] += dec((w.x >> (i * 8)) & 0xFF);
#pragma unroll
  for (int i = 0; i < 4; ++i) s[4 + i] += dec((w.y >> (i * 8)) & 0xFF);
#endif
}

// ---------------------------------------------------------------------------
// partA_prep: blocks < NB partition edges into dst-buckets (LDS staging,
// per-thread flush -- round-7 proved wave-serial flush regresses 3x);
// blocks >= NB do prep (weight transpose+bf16 cast, x -> bf16 + fp8 planes).
// pack = s | ((d & 255) << 17)   (s < 2^17)
// ---------------------------------------------------------------------------
__global__ __launch_bounds__(ATHREADS) void partA_prep_kernel(
    const void* __restrict__ edges, int* __restrict__ bcnt,
    unsigned* __restrict__ part, int* __restrict__ novf, int* __restrict__ ovf,
    const float* __restrict__ x,
    const float* __restrict__ W1l, const float* __restrict__ W1r,
    const float* __restrict__ W2l, const float* __restrict__ W2r,
    unsigned short* __restrict__ Wt1, unsigned short* __restrict__ Wt2,
    unsigned short* __restrict__ xb, unsigned char* __restrict__ x8) {
  __shared__ unsigned stage[NB][SLOTS + 1];  // +1 pad: de-alias flush banks
  __shared__ int scnt[NB];
  __shared__ int sh_i64;
  const int t = threadIdx.x;

  if (blockIdx.x >= NB) {  // ---- prep path (no LDS use) ----
    int bid = blockIdx.x - NB;
    if (bid < NPREP_W) {
      int idx = bid * ATHREADS + t;  // 65536 total
      int layer = idx >> 15;
      int rest = idx & 32767;
      int mat = rest >> 14;
      int r = rest & 16383;
      int k = r >> 7, n = r & 127;
      const float* W = layer ? (mat ? W2r : W2l) : (mat ? W1r : W1l);
      unsigned short* Wt = layer ? Wt2 : Wt1;
      Wt[((size_t)(mat * 128 + n)) * 128 + k] = f2bf(W[k * 128 + n]);
    } else {
      int i = (bid - NPREP_W) * ATHREADS + t;  // one float4 per thread
      if (i < NN * DIM / 4) {
        f32x4 v = ((const f32x4*)x)[i];
        ushort4 hb;
        hb.x = f2bf(v[0]); hb.y = f2bf(v[1]); hb.z = f2bf(v[2]); hb.w = f2bf(v[3]);
        ((ushort4*)xb)[i] = hb;
        uint32_t pk = f2fp8_pair<false>(v[0], v[1], 0);
        pk = f2fp8_pair<true>(v[2], v[3], pk);
        ((uint32_t*)x8)[i] = pk;
      }
    }
    return;
  }

  // ---- partition path ----
  for (int b = t; b < NB; b += ATHREADS) scnt[b] = 0;
  if (t < 64) {
    // int64 little-endian => odd 32-bit words of first 64 entries all zero;
    // int32 => those words are random src values, all-zero impossible.
    int v = ((const int*)edges)[2 * t + 1];
    unsigned long long m = __ballot(v != 0);
    if (t == 0) sh_i64 = (m == 0ull) ? 1 : 0;
  }
  __syncthreads();
  const int i64 = sh_i64;
  const long long ebase = (long long)blockIdx.x * ACHUNK;
  const int nrounds = ACHUNK / ATHREADS;
  for (int r = 0; r < nrounds; ++r) {
    long long e = ebase + (long long)r * ATHREADS + t;
    if (e < EE) {
      int s, d;
      if (i64) {
        s = (int)((const long long*)edges)[e];
        d = (int)((const long long*)edges)[(long long)EE + e];
      } else {
        s = ((const int*)edges)[e];
        d = ((const int*)edges)[(long long)EE + e];
      }
      if ((unsigned)s < NN && (unsigned)d < NN) {
        int b = d >> 8;
        unsigned pk = (unsigned)s | ((unsigned)(d & 255) << 17);
        int pos = atomicAdd(&scnt[b], 1);
        if (pos < SLOTS) {
          stage[b][pos] = pk;
        } else {  // stage overflow (rare): direct append
          int g = atomicAdd(&bcnt[b], 1);
          if (g < BCAP) part[(size_t)b * BCAP + g] = pk;
          else { int oi = atomicAdd(novf, 1); if (oi < OVF_CAP) { ovf[oi*2] = s; ovf[oi*2+1] = d; } }
        }
      }
    }
    __syncthreads();
    const bool last = (r == nrounds - 1);
    for (int b = t; b < NB; b += ATHREADS) {  // per-thread flush (parallel chains)
      int c = scnt[b];
      if (c > SLOTS) c = SLOTS;
      if (c > 0 && (last || c >= FLUSH_AT)) {
        int g = atomicAdd(&bcnt[b], c);
        for (int i = 0; i < c; ++i) {
          int gp = g + i;
          unsigned pk = stage[b][i];
          if (gp < BCAP) {
            part[(size_t)b * BCAP + gp] = pk;
          } else {
            int oi = atomicAdd(novf, 1);
            if (oi < OVF_CAP) { ovf[oi*2] = (int)(pk & 0x1FFFF); ovf[oi*2+1] = (b << 8) | (int)(pk >> 17); }
          }
        }
        scnt[b] = 0;
      }
    }
    __syncthreads();
  }
}

// ---------------------------------------------------------------------------
// Phase B: per bucket (256 nodes), build ELL rows in LDS (LDS atomics),
// write densely coalesced. Also emits cnt (degree).
// ---------------------------------------------------------------------------
__global__ __launch_bounds__(256) void partB_kernel(
    const int* __restrict__ bcnt, const unsigned* __restrict__ part,
    int* __restrict__ cnt, int* __restrict__ ell,
    int* __restrict__ novf, int* __restrict__ ovf) {
  __shared__ int lcnt[256];
  __shared__ int lell[256 * CAP];  // 48 KB
  const int t = threadIdx.x;
  const int b = blockIdx.x;
  lcnt[t] = 0;
  __syncthreads();
  int n = bcnt[b];
  if (n > BCAP) n = BCAP;
  for (int i = t; i < n; i += 256) {
    unsigned pk = part[(size_t)b * BCAP + i];
    int s = (int)(pk & 0x1FFFF);
    int dl = (int)(pk >> 17);
    int pos = atomicAdd(&lcnt[dl], 1);
    if (pos < CAP) lell[dl * CAP + pos] = s;
    else { int oi = atomicAdd(novf, 1); if (oi < OVF_CAP) { ovf[oi*2] = s; ovf[oi*2+1] = (b << 8) | dl; } }
  }
  __syncthreads();
  int4* dst = (int4*)(ell + (size_t)b * 256 * CAP);
  const int4* src = (const int4*)lell;
#pragma unroll
  for (int i = 0; i < 256 * CAP / 4 / 256; ++i) dst[t + i * 256] = src[t + i * 256];
  int node = b * 256 + t;
  if (node < NN) cnt[node] = lcnt[t];
}

// ---------------------------------------------------------------------------
// Gather-aggregate from ELL over fp8 rows (128 B = ONE cache line per nbr).
// One wave per node; quarter-wave per neighbor row (lane = q*16+l, lane owns
// cols l*8..l*8+7 as uint2). 4-deep unroll -> 16 rows in flight per wave.
// f32 accumulate; writes bf16 agg plane.
// ---------------------------------------------------------------------------
__global__ __launch_bounds__(256) void gather_ell_kernel(
    const int* __restrict__ cnt, const int* __restrict__ ell,
    const unsigned char* __restrict__ h8, unsigned short* __restrict__ ahi,
    const int* __restrict__ novf, const int* __restrict__ ovf) {
  const int node = blockIdx.x * 4 + (threadIdx.x >> 6);
  const int lane = threadIdx.x & 63;
  const int q = lane >> 4;       // quarter 0..3
  const int l = lane & 15;       // lane-in-quarter: cols l*8..l*8+7
  if (node >= NN) return;
  const int dcnt = cnt[node];
  const int n = dcnt < CAP ? dcnt : CAP;
  const int* row = ell + (size_t)node * CAP;
  float s[8] = {0.f, 0.f, 0.f, 0.f, 0.f, 0.f, 0.f, 0.f};
  int p = q;
  for (; p + 12 < n; p += 16) {  // 4 independent row loads in flight
    uint2 w0 = *(const uint2*)(h8 + (size_t)row[p] * DIM + l * 8);
    uint2 w1 = *(const uint2*)(h8 + (size_t)row[p + 4] * DIM + l * 8);
    uint2 w2 = *(const uint2*)(h8 + (size_t)row[p + 8] * DIM + l * 8);
    uint2 w3 = *(const uint2*)(h8 + (size_t)row[p + 12] * DIM + l * 8);
    acc_fp8x8(s, w0);
    acc_fp8x8(s, w1);
    acc_fp8x8(s, w2);
    acc_fp8x8(s, w3);
  }
  for (; p < n; p += 4) {
    uint2 w0 = *(const uint2*)(h8 + (size_t)row[p] * DIM + l * 8);
    acc_fp8x8(s, w0);
  }
#pragma unroll
  for (int i = 0; i < 8; ++i) {
    s[i] += __shfl_xor(s[i], 16, 64);
    s[i] += __shfl_xor(s[i], 32, 64);
  }
  if (q == 0) {
    if (dcnt > CAP) {  // overflow fixup: scan tiny list (expected empty)
      int no = *novf;
      if (no > OVF_CAP) no = OVF_CAP;
      for (int i = 0; i < no; ++i) {
        if (ovf[i * 2 + 1] == node) {
          uint2 w0 = *(const uint2*)(h8 + (size_t)ovf[i * 2] * DIM + l * 8);
          acc_fp8x8(s, w0);
        }
      }
    }
    const float rd = 1.0f / fmaxf((float)dcnt, 1.0f);
    uint4 o;
    o.x = pk2(s[0] * rd, s[1] * rd);
    o.y = pk2(s[2] * rd, s[3] * rd);
    o.z = pk2(s[4] * rd, s[5] * rd);
    o.w = pk2(s[6] * rd, s[7] * rd);
    *(uint4*)(ahi + (size_t)node * DIM + l * 8) = o;
  }
}

// ---------------------------------------------------------------------------
// Dense via MFMA: out = act(agg_bf16 @ Wl + bl + h_bf16 @ Wr).
// Pure bf16-plane loads (2 x 16B per fragment pair -> 4 MFMAs), no in-loop
// conversion (round-14's f32-load + cvt chain halved dense throughput).
// WP (layer 1): epilogue writes result IN-PLACE over hb (bf16) and h8 (fp8)
//   -- safe: each block reads only its own 64 rows (before __syncthreads);
//   gather-1 has already completed; no other block reads these rows.
// WOUT (layer 2): writes f32 out only.
// ---------------------------------------------------------------------------
template <bool RELU, bool WP, bool WOUT>
__global__ __launch_bounds__(256, 2) void dense_mfma_kernel(
    const unsigned short* __restrict__ ahi, unsigned short* hb,
    const unsigned short* __restrict__ Wt, const float* __restrict__ bl,
    float* __restrict__ out, unsigned char* ph8, int n) {
  const int t = threadIdx.x;
  const int wave = t >> 6, lane = t & 63;
  const int l15 = lane & 15, l4 = lane >> 4;
  const int base = blockIdx.x * 64;

  bf16x8 bfr[2][4][2];
#pragma unroll
  for (int mat = 0; mat < 2; ++mat)
#pragma unroll
    for (int kt = 0; kt < 4; ++kt)
#pragma unroll
      for (int ntl = 0; ntl < 2; ++ntl) {
        int ncol = (wave * 2 + ntl) * 16 + l15;
        int k0 = kt * 32 + l4 * 8;
        bfr[mat][kt][ntl] = *(const bf16x8*)(Wt + ((size_t)(mat * 128 + ncol)) * 128 + k0);
      }

  f32x4 acc[4][2];
#pragma unroll
  for (int ntl = 0; ntl < 2; ++ntl) {
    float b = bl[(wave * 2 + ntl) * 16 + l15];
#pragma unroll
    for (int rt = 0; rt < 4; ++rt) {
      f32x4 ib = {b, b, b, b};
      acc[rt][ntl] = ib;
    }
  }

#pragma unroll
  for (int kt = 0; kt < 4; ++kt) {
    const int k0 = kt * 32 + l4 * 8;
#pragma unroll
    for (int rt = 0; rt < 4; ++rt) {
      int row = base + rt * 16 + l15;
      if (row >= n) row = n - 1;  // clamp: padded rows computed but never stored
      const size_t off = (size_t)row * DIM + k0;
      bf16x8 a8 = *(const bf16x8*)(ahi + off);
      bf16x8 hh8 = *(const bf16x8*)(hb + off);
#pragma unroll
      for (int ntl = 0; ntl < 2; ++ntl) {
        acc[rt][ntl] = __builtin_amdgcn_mfma_f32_16x16x32_bf16(a8, bfr[0][kt][ntl], acc[rt][ntl], 0, 0, 0);
        acc[rt][ntl] = __builtin_amdgcn_mfma_f32_16x16x32_bf16(hh8, bfr[1][kt][ntl], acc[rt][ntl], 0, 0, 0);
      }
    }
  }

  __syncthreads();  // all hb reads complete before the in-place plane writes

#pragma unroll
  for (int rt = 0; rt < 4; ++rt)
#pragma unroll
    for (int ntl = 0; ntl < 2; ++ntl) {
      const int col = (wave * 2 + ntl) * 16 + l15;
#pragma unroll
      for (int r = 0; r < 4; ++r) {
        int row = base + rt * 16 + l4 * 4 + r;
        if (row < n) {
          float v = acc[rt][ntl][r];
          if (RELU) v = fmaxf(v, 0.f);
          const size_t off = (size_t)row * DIM + col;
          if (WOUT) out[off] = v;
          if (WP) {
            hb[off] = f2bf(v);
            ph8[off] = (unsigned char)(f2fp8_pair<false>(v, v, 0) & 0xFF);
          }
        }
      }
    }
}

// ---------------------------------------------------------------------------
extern "C" void kernel_launch(void* const* d_in, const int* in_sizes, int n_in,
                              void* d_out, int out_size, void* d_ws, size_t ws_size,
                              hipStream_t stream) {
  const float* x   = (const float*)d_in[0];
  const void* edges = d_in[1];
  const float* W1l = (const float*)d_in[2];
  const float* b1l = (const float*)d_in[3];
  const float* W1r = (const float*)d_in[4];
  const float* W2l = (const float*)d_in[5];
  const float* b2l = (const float*)d_in[6];
  const float* W2r = (const float*)d_in[7];
  float* out = (float*)d_out;

  // ---- workspace layout (~84 MB)
  //  * part (7.2 MB) aliases ahi (25.6 MB): part dead after partB, ahi first
  //    written by gather-1.
  //  * h1 planes overwrite x planes IN-PLACE in dense-1's epilogue (each
  //    block touches only rows it already consumed; gather-1 done).
  char* p = (char*)d_ws;
  unsigned short* Wt1 = (unsigned short*)p;               p += 2 * 128 * 128 * 2;
  unsigned short* Wt2 = (unsigned short*)p;               p += 2 * 128 * 128 * 2;
  int* cnt  = (int*)p;                                    p += (size_t)NN * 4;
  int* bcnt = (int*)p;                                    p += (size_t)NB * 4;
  int* novf = (int*)p;                                    p += 4;
  p = (char*)(((uintptr_t)p + 15) & ~(uintptr_t)15);
  int* ovf = (int*)p;                                     p += (size_t)OVF_CAP * 2 * 4;
  p = (char*)(((uintptr_t)p + 255) & ~(uintptr_t)255);
  int* ell = (int*)p;                                     p += (size_t)NB * 256 * CAP * 4;
  p = (char*)(((uintptr_t)p + 255) & ~(uintptr_t)255);
  unsigned short* ahi = (unsigned short*)p;               p += (size_t)NN * DIM * 2;
  unsigned short* hb = (unsigned short*)p;                p += (size_t)NN * DIM * 2;  // x/h1 bf16
  unsigned char* h8 = (unsigned char*)p;                  p += (size_t)NN * DIM;      // x/h1 fp8
  unsigned* part = (unsigned*)ahi;  // alias (disjoint lifetimes)

  // zero bcnt + novf in one memset (cnt fully rewritten by partB)
  (void)hipMemsetAsync(bcnt, 0, ((size_t)NB + 1) * 4, stream);

  // partition + weight/x prep in one grid (prep fills idle CUs)
  partA_prep_kernel<<<NB + NPREP_W + NPREP_X, ATHREADS, 0, stream>>>(
      edges, bcnt, part, novf, ovf, x, W1l, W1r, W2l, W2r, Wt1, Wt2, hb, h8);
  partB_kernel<<<NB, 256, 0, stream>>>(bcnt, part, cnt, ell, novf, ovf);

  const int gather_blocks = (NN + 3) / 4;
  const int dense_blocks = (NN + 63) / 64;

  // ---- layer 1: h1 = relu(mean_agg(x) @ W1l + b1l + x @ W1r)
  //      -> bf16 plane (over hb) + fp8 plane (over h8); no f32 write
  gather_ell_kernel<<<gather_blocks, 256, 0, stream>>>(cnt, ell, h8, ahi, novf, ovf);
  dense_mfma_kernel<true, true, false><<<dense_blocks, 256, 0, stream>>>(
      ahi, hb, Wt1, b1l, out, h8, NN);

  // ---- layer 2: out = mean_agg(h1) @ W2l + b2l + h1 @ W2r -> f32 out
  gather_ell_kernel<<<gather_blocks, 256, 0, stream>>>(cnt, ell, h8, ahi, novf, ovf);
  dense_mfma_kernel<false, false, true><<<dense_blocks, 256, 0, stream>>>(
      ahi, hb, Wt2, b2l, out, nullptr, NN);
}

// Round 16
// 230.438 us; speedup vs baseline: 2.4045x; 1.0020x over previous
//
#include <hip/hip_runtime.h>
#include <cstdint>
#include <cstddef>

#define NN 100000
#define EE 1600000
#define DIM 128
#define CAP 48        // ELL row capacity (mean deg 16; P(deg>48) ~ 5e-11 per node)
#define OVF_CAP 512   // overflow edge capacity (expected 0 used)

#define NB 391        // dst buckets of 256 nodes: ceil(100000/256)
#define BCAP 4608     // per-bucket partition capacity (mean 4092, +8 sigma)
#define SLOTS 32      // LDS staging slots per bucket
#define FLUSH_AT 16   // flush threshold (entries)
#define ACHUNK 4096   // edges per phase-A partition block
#define ATHREADS 512

#define NPREP_W 128                          // weight-prep blocks (65536/512)
#define NPREP_X ((NN * DIM / 4) / ATHREADS)  // x-cast blocks (6250)

#if __has_builtin(__builtin_amdgcn_cvt_pk_f32_fp8) && __has_builtin(__builtin_amdgcn_cvt_pk_fp8_f32)
#define HAVE_FP8 1
#else
#define HAVE_FP8 0
#endif

typedef __attribute__((ext_vector_type(8))) short bf16x8;
typedef __attribute__((ext_vector_type(4))) float f32x4;
typedef __attribute__((ext_vector_type(2))) float f32x2;

__device__ __forceinline__ unsigned short f2bf(float f) {
  union { float f; uint32_t u; } v; v.f = f;
  uint32_t r = v.u + 0x7FFF + ((v.u >> 16) & 1);  // RNE to bf16
  return (unsigned short)(r >> 16);
}
__device__ __forceinline__ uint32_t pk2(float a, float b) {
  return (uint32_t)f2bf(a) | ((uint32_t)f2bf(b) << 16);
}

// ---- fp8 e4m3fn helpers (HW path + software fallback) ----------------------
// NOTE: the builtin's word-select arg must be a LITERAL constant -> template.
template <bool HI>
__device__ __forceinline__ uint32_t f2fp8_pair(float a, float b, uint32_t old) {
#if HAVE_FP8
  return (uint32_t)__builtin_amdgcn_cvt_pk_fp8_f32(a, b, (int)old, HI);
#else
  auto enc = [](float f) -> uint32_t {
    union { float f; uint32_t u; } v; v.f = f;
    uint32_t s = (v.u >> 31) << 7;
    uint32_t m = v.u & 0x7FFFFFFF;
    if (m < 0x3C000000u) {  // < 2^-7: subnormal territory
      union { uint32_t u; float f; } w; w.u = m;
      int q = (int)(w.f * 512.0f + 0.5f);
      if (q > 7) return s | (1u << 3);
      return s | (uint32_t)q;
    }
    uint32_t u2 = m + 0x00080000u;  // round into mantissa bit 20
    int e = (int)(u2 >> 23) - 127;
    if (e > 8) return s | 0x7E;  // clamp to 448
    return s | ((uint32_t)(e + 7) << 3) | ((u2 >> 20) & 7);
  };
  uint32_t pr = enc(a) | (enc(b) << 8);
  return HI ? ((old & 0x0000FFFFu) | (pr << 16)) : ((old & 0xFFFF0000u) | pr);
#endif
}

__device__ __forceinline__ void acc_fp8x8(float* s, uint2 w) {
#if HAVE_FP8
  f32x2 f;
  f = __builtin_amdgcn_cvt_pk_f32_fp8((int)w.x, false); s[0] += f.x; s[1] += f.y;
  f = __builtin_amdgcn_cvt_pk_f32_fp8((int)w.x, true);  s[2] += f.x; s[3] += f.y;
  f = __builtin_amdgcn_cvt_pk_f32_fp8((int)w.y, false); s[4] += f.x; s[5] += f.y;
  f = __builtin_amdgcn_cvt_pk_f32_fp8((int)w.y, true);  s[6] += f.x; s[7] += f.y;
#else
  auto dec = [](uint32_t b) -> float {
    uint32_t sg = (b >> 7) & 1, e = (b >> 3) & 15, m = b & 7;
    if (e == 0) return (sg ? -1.f : 1.f) * (float)m * 0.001953125f;  // m * 2^-9
    union { uint32_t u; float f; } w;
    w.u = (sg << 31) | ((e + 120) << 23) | (m << 20);
    return w.f;
  };
#pragma unroll
  for (int i = 0; i < 4; ++i) s[i] += dec((w.x >> (i * 8)) & 0xFF);
#pragma unroll
  for (int i = 0; i < 4; ++i) s[4 + i] += dec((w.y >> (i * 8)) & 0xFF);
#endif
}

// ---------------------------------------------------------------------------
// partA_prep: blocks < NB partition edges into dst-buckets (LDS staging,
// per-thread flush -- round-7 proved wave-serial flush regresses 3x);
// blocks >= NB do prep (weight transpose+bf16 cast, x -> bf16 + fp8 planes).
// pack = s | ((d & 255) << 17)   (s < 2^17)
// ---------------------------------------------------------------------------
__global__ __launch_bounds__(ATHREADS) void partA_prep_kernel(
    const void* __restrict__ edges, int* __restrict__ bcnt,
    unsigned* __restrict__ part, int* __restrict__ novf, int* __restrict__ ovf,
    const float* __restrict__ x,
    const float* __restrict__ W1l, const float* __restrict__ W1r,
    const float* __restrict__ W2l, const float* __restrict__ W2r,
    unsigned short* __restrict__ Wt1, unsigned short* __restrict__ Wt2,
    unsigned short* __restrict__ xb, unsigned char* __restrict__ x8) {
  __shared__ unsigned stage[NB][SLOTS + 1];  // +1 pad: de-alias flush banks
  __shared__ int scnt[NB];
  __shared__ int sh_i64;
  const int t = threadIdx.x;

  if (blockIdx.x >= NB) {  // ---- prep path (no LDS use) ----
    int bid = blockIdx.x - NB;
    if (bid < NPREP_W) {
      int idx = bid * ATHREADS + t;  // 65536 total
      int layer = idx >> 15;
      int rest = idx & 32767;
      int mat = rest >> 14;
      int r = rest & 16383;
      int k = r >> 7, n = r & 127;
      const float* W = layer ? (mat ? W2r : W2l) : (mat ? W1r : W1l);
      unsigned short* Wt = layer ? Wt2 : Wt1;
      Wt[((size_t)(mat * 128 + n)) * 128 + k] = f2bf(W[k * 128 + n]);
    } else {
      int i = (bid - NPREP_W) * ATHREADS + t;  // one float4 per thread
      if (i < NN * DIM / 4) {
        f32x4 v = ((const f32x4*)x)[i];
        ushort4 hb;
        hb.x = f2bf(v[0]); hb.y = f2bf(v[1]); hb.z = f2bf(v[2]); hb.w = f2bf(v[3]);
        ((ushort4*)xb)[i] = hb;
        uint32_t pk = f2fp8_pair<false>(v[0], v[1], 0);
        pk = f2fp8_pair<true>(v[2], v[3], pk);
        ((uint32_t*)x8)[i] = pk;
      }
    }
    return;
  }

  // ---- partition path ----
  for (int b = t; b < NB; b += ATHREADS) scnt[b] = 0;
  if (t < 64) {
    // int64 little-endian => odd 32-bit words of first 64 entries all zero;
    // int32 => those words are random src values, all-zero impossible.
    int v = ((const int*)edges)[2 * t + 1];
    unsigned long long m = __ballot(v != 0);
    if (t == 0) sh_i64 = (m == 0ull) ? 1 : 0;
  }
  __syncthreads();
  const int i64 = sh_i64;
  const long long ebase = (long long)blockIdx.x * ACHUNK;
  const int nrounds = ACHUNK / ATHREADS;
  for (int r = 0; r < nrounds; ++r) {
    long long e = ebase + (long long)r * ATHREADS + t;
    if (e < EE) {
      int s, d;
      if (i64) {
        s = (int)((const long long*)edges)[e];
        d = (int)((const long long*)edges)[(long long)EE + e];
      } else {
        s = ((const int*)edges)[e];
        d = ((const int*)edges)[(long long)EE + e];
      }
      if ((unsigned)s < NN && (unsigned)d < NN) {
        int b = d >> 8;
        unsigned pk = (unsigned)s | ((unsigned)(d & 255) << 17);
        int pos = atomicAdd(&scnt[b], 1);
        if (pos < SLOTS) {
          stage[b][pos] = pk;
        } else {  // stage overflow (rare): direct append
          int g = atomicAdd(&bcnt[b], 1);
          if (g < BCAP) part[(size_t)b * BCAP + g] = pk;
          else { int oi = atomicAdd(novf, 1); if (oi < OVF_CAP) { ovf[oi*2] = s; ovf[oi*2+1] = d; } }
        }
      }
    }
    __syncthreads();
    const bool last = (r == nrounds - 1);
    for (int b = t; b < NB; b += ATHREADS) {  // per-thread flush (parallel chains)
      int c = scnt[b];
      if (c > SLOTS) c = SLOTS;
      if (c > 0 && (last || c >= FLUSH_AT)) {
        int g = atomicAdd(&bcnt[b], c);
        for (int i = 0; i < c; ++i) {
          int gp = g + i;
          unsigned pk = stage[b][i];
          if (gp < BCAP) {
            part[(size_t)b * BCAP + gp] = pk;
          } else {
            int oi = atomicAdd(novf, 1);
            if (oi < OVF_CAP) { ovf[oi*2] = (int)(pk & 0x1FFFF); ovf[oi*2+1] = (b << 8) | (int)(pk >> 17); }
          }
        }
        scnt[b] = 0;
      }
    }
    __syncthreads();
  }
}

// ---------------------------------------------------------------------------
// Phase B: per bucket (256 nodes), build ELL rows in LDS (LDS atomics),
// write densely coalesced. Also emits cnt (degree).
// ---------------------------------------------------------------------------
__global__ __launch_bounds__(256) void partB_kernel(
    const int* __restrict__ bcnt, const unsigned* __restrict__ part,
    int* __restrict__ cnt, int* __restrict__ ell,
    int* __restrict__ novf, int* __restrict__ ovf) {
  __shared__ int lcnt[256];
  __shared__ int lell[256 * CAP];  // 48 KB
  const int t = threadIdx.x;
  const int b = blockIdx.x;
  lcnt[t] = 0;
  __syncthreads();
  int n = bcnt[b];
  if (n > BCAP) n = BCAP;
  for (int i = t; i < n; i += 256) {
    unsigned pk = part[(size_t)b * BCAP + i];
    int s = (int)(pk & 0x1FFFF);
    int dl = (int)(pk >> 17);
    int pos = atomicAdd(&lcnt[dl], 1);
    if (pos < CAP) lell[dl * CAP + pos] = s;
    else { int oi = atomicAdd(novf, 1); if (oi < OVF_CAP) { ovf[oi*2] = s; ovf[oi*2+1] = (b << 8) | dl; } }
  }
  __syncthreads();
  int4* dst = (int4*)(ell + (size_t)b * 256 * CAP);
  const int4* src = (const int4*)lell;
#pragma unroll
  for (int i = 0; i < 256 * CAP / 4 / 256; ++i) dst[t + i * 256] = src[t + i * 256];
  int node = b * 256 + t;
  if (node < NN) cnt[node] = lcnt[t];
}

// ---------------------------------------------------------------------------
// Gather-aggregate from ELL over fp8 rows (128 B = ONE cache line per nbr).
// One wave per node; quarter-wave per neighbor row (lane = q*16+l, lane owns
// cols l*8..l*8+7 as uint2). 4-deep unroll -> 16 rows in flight per wave.
// f32 accumulate; writes bf16 agg plane.
// ---------------------------------------------------------------------------
__global__ __launch_bounds__(256) void gather_ell_kernel(
    const int* __restrict__ cnt, const int* __restrict__ ell,
    const unsigned char* __restrict__ h8, unsigned short* __restrict__ ahi,
    const int* __restrict__ novf, const int* __restrict__ ovf) {
  const int node = blockIdx.x * 4 + (threadIdx.x >> 6);
  const int lane = threadIdx.x & 63;
  const int q = lane >> 4;       // quarter 0..3
  const int l = lane & 15;       // lane-in-quarter: cols l*8..l*8+7
  if (node >= NN) return;
  const int dcnt = cnt[node];
  const int n = dcnt < CAP ? dcnt : CAP;
  const int* row = ell + (size_t)node * CAP;
  float s[8] = {0.f, 0.f, 0.f, 0.f, 0.f, 0.f, 0.f, 0.f};
  int p = q;
  for (; p + 12 < n; p += 16) {  // 4 independent row loads in flight
    uint2 w0 = *(const uint2*)(h8 + (size_t)row[p] * DIM + l * 8);
    uint2 w1 = *(const uint2*)(h8 + (size_t)row[p + 4] * DIM + l * 8);
    uint2 w2 = *(const uint2*)(h8 + (size_t)row[p + 8] * DIM + l * 8);
    uint2 w3 = *(const uint2*)(h8 + (size_t)row[p + 12] * DIM + l * 8);
    acc_fp8x8(s, w0);
    acc_fp8x8(s, w1);
    acc_fp8x8(s, w2);
    acc_fp8x8(s, w3);
  }
  for (; p < n; p += 4) {
    uint2 w0 = *(const uint2*)(h8 + (size_t)row[p] * DIM + l * 8);
    acc_fp8x8(s, w0);
  }
#pragma unroll
  for (int i = 0; i < 8; ++i) {
    s[i] += __shfl_xor(s[i], 16, 64);
    s[i] += __shfl_xor(s[i], 32, 64);
  }
  if (q == 0) {
    if (dcnt > CAP) {  // overflow fixup: scan tiny list (expected empty)
      int no = *novf;
      if (no > OVF_CAP) no = OVF_CAP;
      for (int i = 0; i < no; ++i) {
        if (ovf[i * 2 + 1] == node) {
          uint2 w0 = *(const uint2*)(h8 + (size_t)ovf[i * 2] * DIM + l * 8);
          acc_fp8x8(s, w0);
        }
      }
    }
    const float rd = 1.0f / fmaxf((float)dcnt, 1.0f);
    uint4 o;
    o.x = pk2(s[0] * rd, s[1] * rd);
    o.y = pk2(s[2] * rd, s[3] * rd);
    o.z = pk2(s[4] * rd, s[5] * rd);
    o.w = pk2(s[6] * rd, s[7] * rd);
    *(uint4*)(ahi + (size_t)node * DIM + l * 8) = o;
  }
}

// ---------------------------------------------------------------------------
// Dense via MFMA: out = act(agg_bf16 @ Wl + bl + h_bf16 @ Wr).
// Pure bf16-plane loads (2 x 16B per fragment pair -> 4 MFMAs), no in-loop
// conversion (round-14's f32-load + cvt chain halved dense throughput).
// WP (layer 1): epilogue writes result IN-PLACE over hb (bf16) and h8 (fp8)
//   -- safe: each block reads only its own 64 rows (before __syncthreads);
//   gather-1 has already completed; no other block reads these rows.
// WOUT (layer 2): writes f32 out only.
// ---------------------------------------------------------------------------
template <bool RELU, bool WP, bool WOUT>
__global__ __launch_bounds__(256, 2) void dense_mfma_kernel(
    const unsigned short* __restrict__ ahi, unsigned short* hb,
    const unsigned short* __restrict__ Wt, const float* __restrict__ bl,
    float* __restrict__ out, unsigned char* ph8, int n) {
  const int t = threadIdx.x;
  const int wave = t >> 6, lane = t & 63;
  const int l15 = lane & 15, l4 = lane >> 4;
  const int base = blockIdx.x * 64;

  bf16x8 bfr[2][4][2];
#pragma unroll
  for (int mat = 0; mat < 2; ++mat)
#pragma unroll
    for (int kt = 0; kt < 4; ++kt)
#pragma unroll
      for (int ntl = 0; ntl < 2; ++ntl) {
        int ncol = (wave * 2 + ntl) * 16 + l15;
        int k0 = kt * 32 + l4 * 8;
        bfr[mat][kt][ntl] = *(const bf16x8*)(Wt + ((size_t)(mat * 128 + ncol)) * 128 + k0);
      }

  f32x4 acc[4][2];
#pragma unroll
  for (int ntl = 0; ntl < 2; ++ntl) {
    float b = bl[(wave * 2 + ntl) * 16 + l15];
#pragma unroll
    for (int rt = 0; rt < 4; ++rt) {
      f32x4 ib = {b, b, b, b};
      acc[rt][ntl] = ib;
    }
  }

#pragma unroll
  for (int kt = 0; kt < 4; ++kt) {
    const int k0 = kt * 32 + l4 * 8;
#pragma unroll
    for (int rt = 0; rt < 4; ++rt) {
      int row = base + rt * 16 + l15;
      if (row >= n) row = n - 1;  // clamp: padded rows computed but never stored
      const size_t off = (size_t)row * DIM + k0;
      bf16x8 a8 = *(const bf16x8*)(ahi + off);
      bf16x8 hh8 = *(const bf16x8*)(hb + off);
#pragma unroll
      for (int ntl = 0; ntl < 2; ++ntl) {
        acc[rt][ntl] = __builtin_amdgcn_mfma_f32_16x16x32_bf16(a8, bfr[0][kt][ntl], acc[rt][ntl], 0, 0, 0);
        acc[rt][ntl] = __builtin_amdgcn_mfma_f32_16x16x32_bf16(hh8, bfr[1][kt][ntl], acc[rt][ntl], 0, 0, 0);
      }
    }
  }

  __syncthreads();  // all hb reads complete before the in-place plane writes

#pragma unroll
  for (int rt = 0; rt < 4; ++rt)
#pragma unroll
    for (int ntl = 0; ntl < 2; ++ntl) {
      const int col = (wave * 2 + ntl) * 16 + l15;
#pragma unroll
      for (int r = 0; r < 4; ++r) {
        int row = base + rt * 16 + l4 * 4 + r;
        if (row < n) {
          float v = acc[rt][ntl][r];
          if (RELU) v = fmaxf(v, 0.f);
          const size_t off = (size_t)row * DIM + col;
          if (WOUT) out[off] = v;
          if (WP) {
            hb[off] = f2bf(v);
            ph8[off] = (unsigned char)(f2fp8_pair<false>(v, v, 0) & 0xFF);
          }
        }
      }
    }
}

// ---------------------------------------------------------------------------
extern "C" void kernel_launch(void* const* d_in, const int* in_sizes, int n_in,
                              void* d_out, int out_size, void* d_ws, size_t ws_size,
                              hipStream_t stream) {
  const float* x   = (const float*)d_in[0];
  const void* edges = d_in[1];
  const float* W1l = (const float*)d_in[2];
  const float* b1l = (const float*)d_in[3];
  const float* W1r = (const float*)d_in[4];
  const float* W2l = (const float*)d_in[5];
  const float* b2l = (const float*)d_in[6];
  const float* W2r = (const float*)d_in[7];
  float* out = (float*)d_out;

  // ---- workspace layout (~84 MB)
  //  * part (7.2 MB) aliases ahi (25.6 MB): part dead after partB, ahi first
  //    written by gather-1.
  //  * h1 planes overwrite x planes IN-PLACE in dense-1's epilogue (each
  //    block touches only rows it already consumed; gather-1 done).
  char* p = (char*)d_ws;
  unsigned short* Wt1 = (unsigned short*)p;               p += 2 * 128 * 128 * 2;
  unsigned short* Wt2 = (unsigned short*)p;               p += 2 * 128 * 128 * 2;
  int* cnt  = (int*)p;                                    p += (size_t)NN * 4;
  int* bcnt = (int*)p;                                    p += (size_t)NB * 4;
  int* novf = (int*)p;                                    p += 4;
  p = (char*)(((uintptr_t)p + 15) & ~(uintptr_t)15);
  int* ovf = (int*)p;                                     p += (size_t)OVF_CAP * 2 * 4;
  p = (char*)(((uintptr_t)p + 255) & ~(uintptr_t)255);
  int* ell = (int*)p;                                     p += (size_t)NB * 256 * CAP * 4;
  p = (char*)(((uintptr_t)p + 255) & ~(uintptr_t)255);
  unsigned short* ahi = (unsigned short*)p;               p += (size_t)NN * DIM * 2;
  unsigned short* hb = (unsigned short*)p;                p += (size_t)NN * DIM * 2;  // x/h1 bf16
  unsigned char* h8 = (unsigned char*)p;                  p += (size_t)NN * DIM;      // x/h1 fp8
  unsigned* part = (unsigned*)ahi;  // alias (disjoint lifetimes)

  // zero bcnt + novf in one memset (cnt fully rewritten by partB)
  (void)hipMemsetAsync(bcnt, 0, ((size_t)NB + 1) * 4, stream);

  // partition + weight/x prep in one grid (prep fills idle CUs)
  partA_prep_kernel<<<NB + NPREP_W + NPREP_X, ATHREADS, 0, stream>>>(
      edges, bcnt, part, novf, ovf, x, W1l, W1r, W2l, W2r, Wt1, Wt2, hb, h8);
  partB_kernel<<<NB, 256, 0, stream>>>(bcnt, part, cnt, ell, novf, ovf);

  const int gather_blocks = (NN + 3) / 4;
  const int dense_blocks = (NN + 63) / 64;

  // ---- layer 1: h1 = relu(mean_agg(x) @ W1l + b1l + x @ W1r)
  //      -> bf16 plane (over hb) + fp8 plane (over h8); no f32 write
  gather_ell_kernel<<<gather_blocks, 256, 0, stream>>>(cnt, ell, h8, ahi, novf, ovf);
  dense_mfma_kernel<true, true, false><<<dense_blocks, 256, 0, stream>>>(
      ahi, hb, Wt1, b1l, out, h8, NN);

  // ---- layer 2: out = mean_agg(h1) @ W2l + b2l + h1 @ W2r -> f32 out
  gather_ell_kernel<<<gather_blocks, 256, 0, stream>>>(cnt, ell, h8, ahi, novf, ovf);
  dense_mfma_kernel<false, false, true><<<dense_blocks, 256, 0, stream>>>(
      ahi, hb, Wt2, b2l, out, nullptr, NN);
}